// Round 2
// baseline (16709.807 us; speedup 1.0000x reference)
//
#include <hip/hip_runtime.h>
#include <hip/hip_cooperative_groups.h>

namespace cg = cooperative_groups;

// ---------------------------------------------------------------------------
// LexicalizedGrammarDecoder — weight-stationary persistent design:
//   prep kernels (one-time) -> enc_coop (128 LSTM steps, 1 cooperative
//   launch, weights in LDS) -> init-MLP / qk / qv GEMMs -> dec_coop (64
//   steps with in-kernel attention phase, 1 cooperative launch).
// ---------------------------------------------------------------------------

constexpr int B_ = 128, S_ = 128, T_ = 64, H_ = 1024;
constexpr int KE_ = 1344;  // enc step K: 320 (emb pad) + 1024 (h)    = 42 chunks
constexpr int KD_ = 1920;  // dec step K: 576 + 320 (ctx pad) + 1024  = 60 chunks
constexpr int KCE = KE_ / 32, KCD = KD_ / 32;

using bf16x8 = __attribute__((ext_vector_type(8))) __bf16;
using f32x4  = __attribute__((ext_vector_type(4))) float;

__device__ __forceinline__ float ldf(const void* p, size_t i, bool bf) {
  return bf ? (float)((const __bf16*)p)[i] : ((const float*)p)[i];
}
__device__ __forceinline__ float sigf(float x) { return 1.f / (1.f + __expf(-x)); }
__device__ __forceinline__ float tanf_(float x) { return 1.f - 2.f / (1.f + __expf(2.f * x)); }

// --- dtype sniffer (same as round 1, which passed) --------------------------
__global__ void sniff(const void* __restrict__ lex, int* __restrict__ flag) {
  if (threadIdx.x == 0 && blockIdx.x == 0) {
    const unsigned short* u = (const unsigned short*)lex;
    int garbage = 0;
    for (int i = 0; i < 64; ++i) {
      unsigned short v = u[1000000 + 2 * i];
      int ex = (v >> 7) & 0xFF;
      bool sane = ((v & 0x7FFF) == 0) || (ex >= 107 && ex <= 147);
      if (!sane) ++garbage;
    }
    *flag = (garbage >= 16) ? 0 : 1;  // 1 => inputs are bf16
  }
}

__global__ void cvt_to_f32(const void* __restrict__ src, float* __restrict__ dst,
                           int n, const int* __restrict__ flag) {
  int i = blockIdx.x * blockDim.x + threadIdx.x;
  bool bf = *flag != 0;
  if (i < n) dst[i] = ldf(src, i, bf);
}

__global__ void f2b(const float* __restrict__ s, __bf16* __restrict__ d, int n) {
  int i = blockIdx.x * blockDim.x + threadIdx.x;
  if (i < n) d[i] = (__bf16)s[i];
}

__global__ void zero_state(__bf16* __restrict__ h, float* __restrict__ c) {
  int i = blockIdx.x * blockDim.x + threadIdx.x;
  if (i < B_ * H_) { h[i] = (__bf16)0.f; c[i] = 0.f; }
}

// --- swizzled step-weight builders ------------------------------------------
// dst layout: [ug(128)][nt(2)][kc][lane(64)][8] bf16 — exactly the per-lane
// MFMA B-fragment order, so the coop kernel's LDS copy is flat and its
// ds_read_b128 per lane is linear (conflict-free).
// Within a ug (8 units): nt0 rows = [i(u0..7), f(u0..7)], nt1 = [g, o].
__global__ void build_w_enc_sw(const void* __restrict__ Wih, const void* __restrict__ Whh,
                               __bf16* __restrict__ W, const int* __restrict__ flag) {
  int bid = blockIdx.x;            // 256 = ug*2 + nt
  int ug = bid >> 1, nt = bid & 1;
  bool bf = *flag != 0;
  for (int i = threadIdx.x; i < KCE * 512; i += blockDim.x) {
    int kc = i >> 9, rem = i & 511, lane = rem >> 3, j = rem & 7;
    int col = lane & 15, quad = lane >> 4;
    int gate = nt * 2 + (col >> 3), ul = col & 7;
    int r = gate * 1024 + ug * 8 + ul;
    int k = kc * 32 + quad * 8 + j;
    float v;
    if (k < 320) v = (k < 300) ? ldf(Wih, (size_t)r * 300 + k, bf) : 0.f;
    else         v = ldf(Whh, (size_t)r * 1024 + (k - 320), bf);
    W[(((size_t)bid * KCE + kc) * 64 + lane) * 8 + j] = (__bf16)v;
  }
}

__global__ void build_w_dec_sw(const void* __restrict__ Wih, const void* __restrict__ Whh,
                               __bf16* __restrict__ W, const int* __restrict__ flag) {
  int bid = blockIdx.x;
  int ug = bid >> 1, nt = bid & 1;
  bool bf = *flag != 0;
  for (int i = threadIdx.x; i < KCD * 512; i += blockDim.x) {
    int kc = i >> 9, rem = i & 511, lane = rem >> 3, j = rem & 7;
    int col = lane & 15, quad = lane >> 4;
    int gate = nt * 2 + (col >> 3), ul = col & 7;
    int r = gate * 1024 + ug * 8 + ul;
    int k = kc * 32 + quad * 8 + j;
    float v;
    if (k < 576)      v = (k < 556) ? ldf(Wih, (size_t)r * 856 + k, bf) : 0.f;
    else if (k < 896) { int kk = k - 576; v = (kk < 300) ? ldf(Wih, (size_t)r * 856 + 556 + kk, bf) : 0.f; }
    else              v = ldf(Whh, (size_t)r * 1024 + (k - 896), bf);
    W[(((size_t)bid * KCD + kc) * 64 + lane) * 8 + j] = (__bf16)v;
  }
}

// generic N-padded, K-exact fp->bf16 weight copy (rows >= N become zero)
__global__ void pad_cvt(const void* __restrict__ src, __bf16* __restrict__ dst,
                        int N, int K, int Kpad, const int* __restrict__ flag) {
  int n = blockIdx.x;
  bool bf = *flag != 0;
  for (int k = threadIdx.x; k < Kpad; k += blockDim.x) {
    float v = (n < N && k < K) ? ldf(src, (size_t)n * K + k, bf) : 0.f;
    dst[(size_t)n * Kpad + k] = (__bf16)v;
  }
}

// --- embedding gathers ------------------------------------------------------
__global__ void gather_emb(const void* __restrict__ lex, const int* __restrict__ seq,
                           __bf16* __restrict__ dst, const int* __restrict__ flag) {
  int blk = blockIdx.x;          // blk = t*B + b
  int t = blk >> 7, b = blk & 127;
  int id = seq[b * S_ + t];
  bool bf = *flag != 0;
  for (int k = threadIdx.x; k < 320; k += blockDim.x) {
    float v = (k < 300) ? ldf(lex, (size_t)id * 300 + k, bf) : 0.f;
    dst[(size_t)blk * 320 + k] = (__bf16)v;
  }
}

__global__ void gather_ans(const void* __restrict__ nt, const void* __restrict__ lex,
                           const int* __restrict__ trg, const int* __restrict__ par,
                           const int* __restrict__ plex, __bf16* __restrict__ dst,
                           const int* __restrict__ flag) {
  int blk = blockIdx.x;          // blk = t*B + b
  int t = blk >> 7, b = blk & 127;
  int i1 = trg[b * T_ + t], i2 = par[b * T_ + t], i3 = plex[b * T_ + t];
  bool bf = *flag != 0;
  for (int k = threadIdx.x; k < 576; k += blockDim.x) {
    float v = 0.f;
    if (k < 128)      v = ldf(nt, (size_t)i1 * 128 + k, bf);
    else if (k < 256) v = ldf(nt, (size_t)i2 * 128 + (k - 128), bf);
    else if (k < 556) v = ldf(lex, (size_t)i3 * 300 + (k - 256), bf);
    dst[(size_t)blk * 576 + k] = (__bf16)v;
  }
}

// --- generic GEMM: C = act(A @ W^T + bias), one 16x16 tile per wave ---------
template <int ACT, bool WB, bool WF>
__global__ __launch_bounds__(256)
void gemm16(const __bf16* __restrict__ A, int lda,
            const __bf16* __restrict__ W, int K,
            const float* __restrict__ bias, int Nreal,
            __bf16* __restrict__ Cb, float* __restrict__ Cf, int ldc) {
  const int lane = threadIdx.x & 63;
  const int wave = threadIdx.x >> 6;
  const int col = lane & 15, quad = lane >> 4, koff = quad * 8;
  const int n0 = blockIdx.x * 16;
  const int m0 = blockIdx.y * 64 + wave * 16;
  f32x4 acc = {0.f, 0.f, 0.f, 0.f};
  const __bf16* ap = A + (size_t)(m0 + col) * lda + koff;
  const __bf16* wp = W + (size_t)(n0 + col) * K + koff;
  for (int k0 = 0; k0 < K; k0 += 32) {
    bf16x8 af = *(const bf16x8*)(ap + k0);
    bf16x8 bf = *(const bf16x8*)(wp + k0);
    acc = __builtin_amdgcn_mfma_f32_16x16x32_bf16(af, bf, acc, 0, 0, 0);
  }
  int n = n0 + col;
  float bv = (n < Nreal) ? bias[n] : 0.f;
#pragma unroll
  for (int r = 0; r < 4; ++r) {
    int m = m0 + quad * 4 + r;
    float v = acc[r] + bv;
    if (ACT == 1) v = fmaxf(v, 0.f);
    if (ACT == 2) v = tanf_(v);
    size_t idx = (size_t)m * ldc + n;
    if (WB) Cb[idx] = (__bf16)v;
    if (WF) Cf[idx] = v;
  }
}

// transpose q_key (b*128+s, 112-ld) -> qkT[b][100][128] for coalesced energy
__global__ void transpose_qk(const float* __restrict__ q, float* __restrict__ qT) {
  int b = blockIdx.x;
  for (int i = threadIdx.x; i < 100 * 128; i += blockDim.x) {
    int k = i >> 7, s = i & 127;
    qT[((size_t)b * 100 + k) * 128 + s] = q[((size_t)b * 128 + s) * 112 + k];
  }
}

// ---------------------------------------------------------------------------
// Persistent cooperative encoder: 256 blocks (1/CU), weights in LDS.
// block bb: ug = bb>>1 (8 hidden units), mh = bb&1 (64 batch rows).
// ---------------------------------------------------------------------------
struct EncArgs {
  const __bf16* wE; const float* bEncF; const __bf16* embE;
  __bf16* h0; __bf16* h1; float* cE; const int* lens; __bf16* SH;
};

__global__ __launch_bounds__(256, 1)
void enc_coop(EncArgs a) {
  extern __shared__ char smem[];
  __bf16* Wl = (__bf16*)smem;                      // 2*KCE*64*8 = 43008 bf16
  float* zb = (float*)(smem + 2 * KCE * 512 * 2);  // 64*33 f32 (+1 pad: banks)
  const int bb = blockIdx.x;
  const int ug = bb >> 1, mh = bb & 1;
  // one-time LDS weight load (flat copy, already fragment-ordered)
  {
    const uint4* src = (const uint4*)(a.wE + (size_t)ug * 2 * KCE * 512);
    uint4* dst = (uint4*)Wl;
    for (int i = threadIdx.x; i < 2 * KCE * 512 * 2 / 16; i += 256) dst[i] = src[i];
  }
  __syncthreads();
  cg::grid_group grid = cg::this_grid();
  const int lane = threadIdx.x & 63, wave = threadIdx.x >> 6;
  const int col = lane & 15, quad = lane >> 4, koff = quad * 8;
  const int am = mh * 64 + wave * 16 + col;

  for (int t = 0; t < S_; ++t) {
    const __bf16* hR = (t & 1) ? a.h1 : a.h0;
    __bf16* hW = (t & 1) ? a.h0 : a.h1;
    f32x4 acc0 = {0.f, 0.f, 0.f, 0.f}, acc1 = {0.f, 0.f, 0.f, 0.f};
    const __bf16* embRow = a.embE + ((size_t)t * B_ + am) * 320 + koff;
    const __bf16* hRow = hR + (size_t)am * H_ + koff;
#pragma unroll
    for (int kc = 0; kc < KCE; ++kc) {
      const int k0 = kc * 32;
      const __bf16* ap = (k0 < 320) ? (embRow + k0) : (hRow + (k0 - 320));
      bf16x8 af = *(const bf16x8*)ap;
      bf16x8 b0 = *(const bf16x8*)(Wl + ((size_t)(0 * KCE + kc) * 64 + lane) * 8);
      bf16x8 b1 = *(const bf16x8*)(Wl + ((size_t)(1 * KCE + kc) * 64 + lane) * 8);
      acc0 = __builtin_amdgcn_mfma_f32_16x16x32_bf16(af, b0, acc0, 0, 0, 0);
      acc1 = __builtin_amdgcn_mfma_f32_16x16x32_bf16(af, b1, acc1, 0, 0, 0);
    }
#pragma unroll
    for (int r = 0; r < 4; ++r) {
      int ml = wave * 16 + quad * 4 + r;
      zb[ml * 33 + col] = acc0[r];        // rows 0..15 = i(u),f(u)
      zb[ml * 33 + 16 + col] = acc1[r];   // rows 16..31 = g(u),o(u)
    }
    __syncthreads();
#pragma unroll
    for (int p = 0; p < 2; ++p) {
      int idx = threadIdx.x + p * 256;
      int ml = idx >> 3, u = idx & 7;
      int m = mh * 64 + ml, j = ug * 8 + u;
      float ig = sigf(zb[ml * 33 + u]      + a.bEncF[j]);
      float fg = sigf(zb[ml * 33 + 8 + u]  + a.bEncF[1024 + j]);
      float gg = tanf_(zb[ml * 33 + 16 + u] + a.bEncF[2048 + j]);
      float og = sigf(zb[ml * 33 + 24 + u] + a.bEncF[3072 + j]);
      size_t sidx = (size_t)m * H_ + j;
      float cOld = a.cE[sidx];
      float c2 = fg * cOld + ig * gg;
      float h2 = og * tanf_(c2);
      bool valid = t < a.lens[m];
      a.cE[sidx] = valid ? c2 : cOld;
      hW[sidx] = valid ? (__bf16)h2 : hR[sidx];
      a.SH[((size_t)m * S_ + t) * H_ + j] = valid ? (__bf16)h2 : (__bf16)0.f;
    }
    grid.sync();
  }
}

// ---------------------------------------------------------------------------
// Persistent cooperative decoder: per step, phase A = attention (blocks
// 0..127, one per batch row), grid sync, phase B = LSTM step (all blocks).
// ---------------------------------------------------------------------------
struct DecArgs {
  const __bf16* wD; const float* bDecF; const __bf16* ansP;
  __bf16* h0; __bf16* h1; float* cD; const int* lens;
  const float* waF; const float* baF; const float* qkT; const float* qval;
  __bf16* ctx; void* out; const int* flag;
};

__global__ __launch_bounds__(256, 1)
void dec_coop(DecArgs a) {
  extern __shared__ char smem[];
  __bf16* Wl = (__bf16*)smem;                      // 2*KCD*64*8 = 61440 bf16
  float* zb = (float*)(smem + 2 * KCD * 512 * 2);  // 64*33 f32; attn overlay:
  float* hs = zb;            // 1024
  float* ak = zb + 1024;     // 112
  float* wts = zb + 1136;    // 128
  float* sc = zb + 1264;     // 128   (total 1392 <= 2112)
  const int bb = blockIdx.x;
  const int ug = bb >> 1, mh = bb & 1;
  {
    const uint4* src = (const uint4*)(a.wD + (size_t)ug * 2 * KCD * 512);
    uint4* dst = (uint4*)Wl;
    for (int i = threadIdx.x; i < 2 * KCD * 512 * 2 / 16; i += 256) dst[i] = src[i];
  }
  __syncthreads();
  cg::grid_group grid = cg::this_grid();
  const int tid = threadIdx.x;
  const int lane = tid & 63, wave = tid >> 6;
  const int col = lane & 15, quad = lane >> 4, koff = quad * 8;
  const int am = mh * 64 + wave * 16 + col;
  const bool obf = *a.flag != 0;

  for (int t = 0; t < T_; ++t) {
    const __bf16* hR = (t & 1) ? a.h1 : a.h0;
    __bf16* hW = (t & 1) ? a.h0 : a.h1;
    // ---- phase A: attention for b = bb (blocks 0..127) ----
    if (bb < B_) {
      const int b = bb;
      for (int k = tid; k < H_; k += 256) hs[k] = (float)hR[(size_t)b * H_ + k];
      __syncthreads();
      for (int n = wave; n < 100; n += 4) {
        float acc = 0.f;
        for (int k = lane; k < H_; k += 64) acc += hs[k] * a.waF[(size_t)n * H_ + k];
#pragma unroll
        for (int off = 32; off > 0; off >>= 1) acc += __shfl_down(acc, off);
        if (lane == 0) ak[n] = tanf_(acc + a.baF[n]);
      }
      __syncthreads();
      int len = a.lens[b];
      if (tid < S_) {
        float e = -1e30f;
        if (tid < len) {
          float acc = 0.f;
#pragma unroll 4
          for (int k = 0; k < 100; ++k) acc += a.qkT[((size_t)b * 100 + k) * 128 + tid] * ak[k];
          e = acc;
        }
        wts[tid] = e; sc[tid] = e;
      }
      __syncthreads();
      for (int off = 64; off > 0; off >>= 1) {
        if (tid < off) sc[tid] = fmaxf(sc[tid], sc[tid + off]);
        __syncthreads();
      }
      float mx = sc[0];
      __syncthreads();
      if (tid < S_) {
        float ex = (wts[tid] <= -1e29f) ? 0.f : __expf(wts[tid] - mx);
        wts[tid] = ex; sc[tid] = ex;
      }
      __syncthreads();
      for (int off = 64; off > 0; off >>= 1) {
        if (tid < off) sc[tid] += sc[tid + off];
        __syncthreads();
      }
      float inv = 1.f / sc[0];
      for (int d = tid; d < 320; d += 256) {
        float v = 0.f;
        if (d < 300) {
          for (int s = 0; s < S_; ++s) v += wts[s] * a.qval[((size_t)b * S_ + s) * 304 + d];
          v *= inv;
        }
        a.ctx[(size_t)b * 320 + d] = (__bf16)v;
      }
    }
    grid.sync();
    // ---- phase B: LSTM step (all blocks) ----
    f32x4 acc0 = {0.f, 0.f, 0.f, 0.f}, acc1 = {0.f, 0.f, 0.f, 0.f};
    const __bf16* ansRow = a.ansP + ((size_t)t * B_ + am) * 576 + koff;
    const __bf16* ctxRow = a.ctx + (size_t)am * 320 + koff;
    const __bf16* hRow = hR + (size_t)am * H_ + koff;
#pragma unroll
    for (int kc = 0; kc < KCD; ++kc) {
      const int k0 = kc * 32;
      const __bf16* ap;
      if (k0 < 576)      ap = ansRow + k0;
      else if (k0 < 896) ap = ctxRow + (k0 - 576);
      else               ap = hRow + (k0 - 896);
      bf16x8 af = *(const bf16x8*)ap;
      bf16x8 b0 = *(const bf16x8*)(Wl + ((size_t)(0 * KCD + kc) * 64 + lane) * 8);
      bf16x8 b1 = *(const bf16x8*)(Wl + ((size_t)(1 * KCD + kc) * 64 + lane) * 8);
      acc0 = __builtin_amdgcn_mfma_f32_16x16x32_bf16(af, b0, acc0, 0, 0, 0);
      acc1 = __builtin_amdgcn_mfma_f32_16x16x32_bf16(af, b1, acc1, 0, 0, 0);
    }
    __syncthreads();  // attn overlay done; reuse zb
#pragma unroll
    for (int r = 0; r < 4; ++r) {
      int ml = wave * 16 + quad * 4 + r;
      zb[ml * 33 + col] = acc0[r];
      zb[ml * 33 + 16 + col] = acc1[r];
    }
    __syncthreads();
#pragma unroll
    for (int p = 0; p < 2; ++p) {
      int idx = tid + p * 256;
      int ml = idx >> 3, u = idx & 7;
      int m = mh * 64 + ml, j = ug * 8 + u;
      float ig = sigf(zb[ml * 33 + u]      + a.bDecF[j]);
      float fg = sigf(zb[ml * 33 + 8 + u]  + a.bDecF[1024 + j]);
      float gg = tanf_(zb[ml * 33 + 16 + u] + a.bDecF[2048 + j]);
      float og = sigf(zb[ml * 33 + 24 + u] + a.bDecF[3072 + j]);
      size_t sidx = (size_t)m * H_ + j;
      float cOld = a.cD[sidx];
      float c2 = fg * cOld + ig * gg;
      float h2 = og * tanf_(c2);
      a.cD[sidx] = c2;
      hW[sidx] = (__bf16)h2;
      size_t oidx = ((size_t)m * T_ + t) * H_ + j;
      if (obf) ((__bf16*)a.out)[oidx] = (__bf16)h2;
      else     ((float*)a.out)[oidx] = h2;
    }
    grid.sync();
  }
}

// ---------------------------------------------------------------------------
extern "C" void kernel_launch(void* const* d_in, const int* in_sizes, int n_in,
                              void* d_out, int out_size, void* d_ws, size_t ws_size,
                              hipStream_t stream) {
  const int* src_seqs = (const int*)d_in[0];
  const int* src_len  = (const int*)d_in[1];
  const int* trg_nt   = (const int*)d_in[2];
  const int* par_nt   = (const int*)d_in[3];
  const int* par_lex  = (const int*)d_in[4];
  const void* lex_emb = d_in[5];
  const void* nt_emb  = d_in[6];
  const void* encWih  = d_in[7];
  const void* encWhh  = d_in[8];
  const void* encB    = d_in[9];
  const void* decWih  = d_in[10];
  const void* decWhh  = d_in[11];
  const void* decB    = d_in[12];
  const void* Wh1 = d_in[13]; const void* bh1 = d_in[14];
  const void* Wh2 = d_in[15]; const void* bh2 = d_in[16];
  const void* Wc1 = d_in[17]; const void* bc1 = d_in[18];
  const void* Wc2 = d_in[19]; const void* bc2 = d_in[20];
  const void* Wa  = d_in[21]; const void* ba  = d_in[22];
  const void* Wqk = d_in[23]; const void* bqk = d_in[24];
  const void* Wqv = d_in[25]; const void* bqv = d_in[26];

  char* base = (char*)d_ws;
  size_t off = 0;
  auto alloc = [&](size_t bytes) -> char* {
    char* p = base + off;
    off += (bytes + 255) & ~(size_t)255;
    return p;
  };
  __bf16* wEnc = (__bf16*)alloc((size_t)4096 * KE_ * 2);
  float*  bEncF = (float*)alloc(4096 * 4);
  __bf16* wDec = (__bf16*)alloc((size_t)4096 * KD_ * 2);
  float*  bDecF = (float*)alloc(4096 * 4);
  __bf16* embE = (__bf16*)alloc((size_t)S_ * B_ * 320 * 2);
  __bf16* ansP = (__bf16*)alloc((size_t)T_ * B_ * 576 * 2);
  __bf16* SH   = (__bf16*)alloc((size_t)B_ * S_ * H_ * 2);
  __bf16* wh1p = (__bf16*)alloc((size_t)2048 * 1024 * 2);
  __bf16* wh2p = (__bf16*)alloc((size_t)1024 * 2048 * 2);
  __bf16* wc1p = (__bf16*)alloc((size_t)2048 * 1024 * 2);
  __bf16* wc2p = (__bf16*)alloc((size_t)1024 * 2048 * 2);
  __bf16* wqkp = (__bf16*)alloc((size_t)112 * 1024 * 2);
  __bf16* wqvp = (__bf16*)alloc((size_t)304 * 1024 * 2);
  float*  qkey = (float*)alloc((size_t)B_ * S_ * 112 * 4);
  float*  qkT  = (float*)alloc((size_t)B_ * 100 * 128 * 4);
  float*  qval = (float*)alloc((size_t)B_ * S_ * 304 * 4);
  __bf16* hE0 = (__bf16*)alloc((size_t)B_ * H_ * 2);
  __bf16* hE1 = (__bf16*)alloc((size_t)B_ * H_ * 2);
  float*  cE  = (float*)alloc((size_t)B_ * H_ * 4);
  __bf16* cEb = (__bf16*)alloc((size_t)B_ * H_ * 2);
  __bf16* t1b = (__bf16*)alloc((size_t)B_ * 2048 * 2);
  __bf16* t2b = (__bf16*)alloc((size_t)B_ * 2048 * 2);
  __bf16* hD0 = (__bf16*)alloc((size_t)B_ * H_ * 2);
  __bf16* hD1 = (__bf16*)alloc((size_t)B_ * H_ * 2);
  float*  cD  = (float*)alloc((size_t)B_ * H_ * 4);
  __bf16* ctx = (__bf16*)alloc((size_t)B_ * 320 * 2);
  float*  waF  = (float*)alloc((size_t)100 * 1024 * 4);
  float*  bh1F = (float*)alloc(2048 * 4);
  float*  bh2F = (float*)alloc(1024 * 4);
  float*  bc1F = (float*)alloc(2048 * 4);
  float*  bc2F = (float*)alloc(1024 * 4);
  float*  baF  = (float*)alloc(112 * 4);
  float*  bqkF = (float*)alloc(112 * 4);
  float*  bqvF = (float*)alloc(304 * 4);
  int*    flag = (int*)alloc(256);
  if (off > ws_size) return;

  // ---- prep ----
  sniff<<<1, 64, 0, stream>>>(lex_emb, flag);
  cvt_to_f32<<<400, 256, 0, stream>>>(Wa, waF, 102400, flag);
  cvt_to_f32<<<16, 256, 0, stream>>>(encB, bEncF, 4096, flag);
  cvt_to_f32<<<16, 256, 0, stream>>>(decB, bDecF, 4096, flag);
  cvt_to_f32<<<8, 256, 0, stream>>>(bh1, bh1F, 2048, flag);
  cvt_to_f32<<<4, 256, 0, stream>>>(bh2, bh2F, 1024, flag);
  cvt_to_f32<<<8, 256, 0, stream>>>(bc1, bc1F, 2048, flag);
  cvt_to_f32<<<4, 256, 0, stream>>>(bc2, bc2F, 1024, flag);
  cvt_to_f32<<<1, 256, 0, stream>>>(ba, baF, 100, flag);
  cvt_to_f32<<<1, 256, 0, stream>>>(bqk, bqkF, 100, flag);
  cvt_to_f32<<<2, 256, 0, stream>>>(bqv, bqvF, 300, flag);
  build_w_enc_sw<<<256, 512, 0, stream>>>(encWih, encWhh, wEnc, flag);
  build_w_dec_sw<<<256, 512, 0, stream>>>(decWih, decWhh, wDec, flag);
  pad_cvt<<<2048, 256, 0, stream>>>(Wh1, wh1p, 2048, 1024, 1024, flag);
  pad_cvt<<<1024, 256, 0, stream>>>(Wh2, wh2p, 1024, 2048, 2048, flag);
  pad_cvt<<<2048, 256, 0, stream>>>(Wc1, wc1p, 2048, 1024, 1024, flag);
  pad_cvt<<<1024, 256, 0, stream>>>(Wc2, wc2p, 1024, 2048, 2048, flag);
  pad_cvt<<<112, 256, 0, stream>>>(Wqk, wqkp, 100, 1024, 1024, flag);
  pad_cvt<<<304, 256, 0, stream>>>(Wqv, wqvp, 300, 1024, 1024, flag);
  gather_emb<<<S_ * B_, 256, 0, stream>>>(lex_emb, src_seqs, embE, flag);
  gather_ans<<<T_ * B_, 256, 0, stream>>>(nt_emb, lex_emb, trg_nt, par_nt, par_lex, ansP, flag);
  zero_state<<<512, 256, 0, stream>>>(hE0, cE);

  // ---- encoder: one cooperative launch, 128 steps ----
  const unsigned encLds = 2 * KCE * 512 * 2 + 64 * 33 * 4;   // 94464 B
  const unsigned decLds = 2 * KCD * 512 * 2 + 64 * 33 * 4;   // 131328 B
  hipFuncSetAttribute((const void*)enc_coop, hipFuncAttributeMaxDynamicSharedMemorySize, encLds);
  hipFuncSetAttribute((const void*)dec_coop, hipFuncAttributeMaxDynamicSharedMemorySize, decLds);

  EncArgs ea = {wEnc, bEncF, embE, hE0, hE1, cE, src_len, SH};
  void* eargs[] = {&ea};
  hipLaunchCooperativeKernel((const void*)enc_coop, dim3(256), dim3(256), eargs, encLds, stream);

  // ---- decoder init MLPs (final enc state in hE0 / cE) ----
  f2b<<<512, 256, 0, stream>>>(cE, cEb, B_ * H_);
  gemm16<1, true, false><<<dim3(128, 2), 256, 0, stream>>>(hE0, 1024, wh1p, 1024, bh1F, 2048, t1b, nullptr, 2048);
  gemm16<0, true, false><<<dim3(64, 2), 256, 0, stream>>>(t1b, 2048, wh2p, 2048, bh2F, 1024, hD0, nullptr, 1024);
  gemm16<1, true, false><<<dim3(128, 2), 256, 0, stream>>>(cEb, 1024, wc1p, 1024, bc1F, 2048, t2b, nullptr, 2048);
  gemm16<0, false, true><<<dim3(64, 2), 256, 0, stream>>>(t2b, 2048, wc2p, 2048, bc2F, 1024, nullptr, cD, 1024);

  // ---- attention keys/values over all (b,s) ----
  gemm16<2, false, true><<<dim3(7, 256), 256, 0, stream>>>(SH, 1024, wqkp, 1024, bqkF, 100, nullptr, qkey, 112);
  transpose_qk<<<B_, 256, 0, stream>>>(qkey, qkT);
  gemm16<0, false, true><<<dim3(19, 256), 256, 0, stream>>>(SH, 1024, wqvp, 1024, bqvF, 300, nullptr, qval, 304);

  // ---- decoder: one cooperative launch, 64 steps w/ in-kernel attention ----
  DecArgs da = {wDec, bDecF, ansP, hD0, hD1, cD, src_len,
                waF, baF, qkT, qval, ctx, d_out, flag};
  void* dargs[] = {&da};
  hipLaunchCooperativeKernel((const void*)dec_coop, dim3(256), dim3(256), dargs, decLds, stream);
}

// Round 3
// 5675.811 us; speedup vs baseline: 2.9440x; 2.9440x over previous
//
#include <hip/hip_runtime.h>

// ---------------------------------------------------------------------------
// LexicalizedGrammarDecoder — weight-stationary persistent design with a
// FENCE-FREE custom grid barrier:
//   - cross-block data (h, ctx) published via agent-scope relaxed atomic
//     stores (bypass L2 -> coherence point) and read via agent-scope atomic
//     loads. No __threadfence, so L2 stays warm (weights/LDS, Wa, qkT, qval).
//   - barrier: __syncthreads (drains vmcnt => publications complete) ->
//     master atomicAdd into 16 slots -> 16 lanes spin on bypass loads.
// ROCm cg::grid.sync() measured ~40us/step (R2: MfmaUtil 0.46%, 354MB FETCH
// from per-step L2 invalidation); this replaces it.
// ---------------------------------------------------------------------------

constexpr int B_ = 128, S_ = 128, T_ = 64, H_ = 1024;
constexpr int KE_ = 1344;  // enc step K: 320 (emb pad) + 1024 (h)    = 42 chunks
constexpr int KD_ = 1920;  // dec step K: 576 + 320 (ctx pad) + 1024  = 60 chunks
constexpr int KCE = KE_ / 32, KCD = KD_ / 32;

using bf16x8 = __attribute__((ext_vector_type(8))) __bf16;
using f32x4  = __attribute__((ext_vector_type(4))) float;
using ull = unsigned long long;

union Pack8 { ull q[2]; bf16x8 v; };

__device__ __forceinline__ float ldf(const void* p, size_t i, bool bf) {
  return bf ? (float)((const __bf16*)p)[i] : ((const float*)p)[i];
}
__device__ __forceinline__ float sigf(float x) { return 1.f / (1.f + __expf(-x)); }
__device__ __forceinline__ float tanf_(float x) { return 1.f - 2.f / (1.f + __expf(2.f * x)); }

__device__ __forceinline__ ull al8(const ull* p) {
  return __hip_atomic_load(p, __ATOMIC_RELAXED, __HIP_MEMORY_SCOPE_AGENT);
}
__device__ __forceinline__ void as8(ull* p, ull v) {
  __hip_atomic_store(p, v, __ATOMIC_RELAXED, __HIP_MEMORY_SCOPE_AGENT);
}

// Fence-free grid barrier: 256 blocks, 16 slots x 16 arrivals, epoch-based.
__device__ __forceinline__ void gbar(unsigned* bar, int bb, unsigned ep) {
  __syncthreads();  // drains vmcnt: this block's atomic publications are at L3
  if (threadIdx.x == 0)
    __hip_atomic_fetch_add(&bar[(bb & 15) * 32], 1u, __ATOMIC_RELAXED,
                           __HIP_MEMORY_SCOPE_AGENT);
  if (threadIdx.x < 16) {
    const unsigned tgt = ep * 16;
    while (__hip_atomic_load(&bar[threadIdx.x * 32], __ATOMIC_RELAXED,
                             __HIP_MEMORY_SCOPE_AGENT) < tgt)
      __builtin_amdgcn_s_sleep(2);
  }
  __syncthreads();
}

// --- dtype sniffer ----------------------------------------------------------
__global__ void sniff(const void* __restrict__ lex, int* __restrict__ flag) {
  if (threadIdx.x == 0 && blockIdx.x == 0) {
    const unsigned short* u = (const unsigned short*)lex;
    int garbage = 0;
    for (int i = 0; i < 64; ++i) {
      unsigned short v = u[1000000 + 2 * i];
      int ex = (v >> 7) & 0xFF;
      bool sane = ((v & 0x7FFF) == 0) || (ex >= 107 && ex <= 147);
      if (!sane) ++garbage;
    }
    *flag = (garbage >= 16) ? 0 : 1;  // 1 => inputs are bf16
  }
}

__global__ void cvt_to_f32(const void* __restrict__ src, float* __restrict__ dst,
                           int n, const int* __restrict__ flag) {
  int i = blockIdx.x * blockDim.x + threadIdx.x;
  bool bf = *flag != 0;
  if (i < n) dst[i] = ldf(src, i, bf);
}

__global__ void f2b(const float* __restrict__ s, __bf16* __restrict__ d, int n) {
  int i = blockIdx.x * blockDim.x + threadIdx.x;
  if (i < n) d[i] = (__bf16)s[i];
}

__global__ void zero_state(__bf16* __restrict__ h, float* __restrict__ c) {
  int i = blockIdx.x * blockDim.x + threadIdx.x;
  if (i < B_ * H_) { h[i] = (__bf16)0.f; c[i] = 0.f; }
}

__global__ void zero_bar(unsigned* __restrict__ bar) {
  bar[threadIdx.x] = 0u;
}

// --- swizzled step-weight builders (verified in R1/R2) ----------------------
// dst: [ug(128)][nt(2)][kc][lane(64)][8] bf16 = per-lane MFMA B-fragment order.
__global__ void build_w_enc_sw(const void* __restrict__ Wih, const void* __restrict__ Whh,
                               __bf16* __restrict__ W, const int* __restrict__ flag) {
  int bid = blockIdx.x;            // 256 = ug*2 + nt
  int ug = bid >> 1, nt = bid & 1;
  bool bf = *flag != 0;
  for (int i = threadIdx.x; i < KCE * 512; i += blockDim.x) {
    int kc = i >> 9, rem = i & 511, lane = rem >> 3, j = rem & 7;
    int col = lane & 15, quad = lane >> 4;
    int gate = nt * 2 + (col >> 3), ul = col & 7;
    int r = gate * 1024 + ug * 8 + ul;
    int k = kc * 32 + quad * 8 + j;
    float v;
    if (k < 320) v = (k < 300) ? ldf(Wih, (size_t)r * 300 + k, bf) : 0.f;
    else         v = ldf(Whh, (size_t)r * 1024 + (k - 320), bf);
    W[(((size_t)bid * KCE + kc) * 64 + lane) * 8 + j] = (__bf16)v;
  }
}

__global__ void build_w_dec_sw(const void* __restrict__ Wih, const void* __restrict__ Whh,
                               __bf16* __restrict__ W, const int* __restrict__ flag) {
  int bid = blockIdx.x;
  int ug = bid >> 1, nt = bid & 1;
  bool bf = *flag != 0;
  for (int i = threadIdx.x; i < KCD * 512; i += blockDim.x) {
    int kc = i >> 9, rem = i & 511, lane = rem >> 3, j = rem & 7;
    int col = lane & 15, quad = lane >> 4;
    int gate = nt * 2 + (col >> 3), ul = col & 7;
    int r = gate * 1024 + ug * 8 + ul;
    int k = kc * 32 + quad * 8 + j;
    float v;
    if (k < 576)      v = (k < 556) ? ldf(Wih, (size_t)r * 856 + k, bf) : 0.f;
    else if (k < 896) { int kk = k - 576; v = (kk < 300) ? ldf(Wih, (size_t)r * 856 + 556 + kk, bf) : 0.f; }
    else              v = ldf(Whh, (size_t)r * 1024 + (k - 896), bf);
    W[(((size_t)bid * KCD + kc) * 64 + lane) * 8 + j] = (__bf16)v;
  }
}

__global__ void pad_cvt(const void* __restrict__ src, __bf16* __restrict__ dst,
                        int N, int K, int Kpad, const int* __restrict__ flag) {
  int n = blockIdx.x;
  bool bf = *flag != 0;
  for (int k = threadIdx.x; k < Kpad; k += blockDim.x) {
    float v = (n < N && k < K) ? ldf(src, (size_t)n * K + k, bf) : 0.f;
    dst[(size_t)n * Kpad + k] = (__bf16)v;
  }
}

// --- embedding gathers ------------------------------------------------------
__global__ void gather_emb(const void* __restrict__ lex, const int* __restrict__ seq,
                           __bf16* __restrict__ dst, const int* __restrict__ flag) {
  int blk = blockIdx.x;          // blk = t*B + b
  int t = blk >> 7, b = blk & 127;
  int id = seq[b * S_ + t];
  bool bf = *flag != 0;
  for (int k = threadIdx.x; k < 320; k += blockDim.x) {
    float v = (k < 300) ? ldf(lex, (size_t)id * 300 + k, bf) : 0.f;
    dst[(size_t)blk * 320 + k] = (__bf16)v;
  }
}

__global__ void gather_ans(const void* __restrict__ nt, const void* __restrict__ lex,
                           const int* __restrict__ trg, const int* __restrict__ par,
                           const int* __restrict__ plex, __bf16* __restrict__ dst,
                           const int* __restrict__ flag) {
  int blk = blockIdx.x;          // blk = t*B + b
  int t = blk >> 7, b = blk & 127;
  int i1 = trg[b * T_ + t], i2 = par[b * T_ + t], i3 = plex[b * T_ + t];
  bool bf = *flag != 0;
  for (int k = threadIdx.x; k < 576; k += blockDim.x) {
    float v = 0.f;
    if (k < 128)      v = ldf(nt, (size_t)i1 * 128 + k, bf);
    else if (k < 256) v = ldf(nt, (size_t)i2 * 128 + (k - 128), bf);
    else if (k < 556) v = ldf(lex, (size_t)i3 * 300 + (k - 256), bf);
    dst[(size_t)blk * 576 + k] = (__bf16)v;
  }
}

// --- generic GEMM: C = act(A @ W^T + bias), one 16x16 tile per wave ---------
template <int ACT, bool WB, bool WF>
__global__ __launch_bounds__(256)
void gemm16(const __bf16* __restrict__ A, int lda,
            const __bf16* __restrict__ W, int K,
            const float* __restrict__ bias, int Nreal,
            __bf16* __restrict__ Cb, float* __restrict__ Cf, int ldc) {
  const int lane = threadIdx.x & 63;
  const int wave = threadIdx.x >> 6;
  const int col = lane & 15, quad = lane >> 4, koff = quad * 8;
  const int n0 = blockIdx.x * 16;
  const int m0 = blockIdx.y * 64 + wave * 16;
  f32x4 acc = {0.f, 0.f, 0.f, 0.f};
  const __bf16* ap = A + (size_t)(m0 + col) * lda + koff;
  const __bf16* wp = W + (size_t)(n0 + col) * K + koff;
  for (int k0 = 0; k0 < K; k0 += 32) {
    bf16x8 af = *(const bf16x8*)(ap + k0);
    bf16x8 bf = *(const bf16x8*)(wp + k0);
    acc = __builtin_amdgcn_mfma_f32_16x16x32_bf16(af, bf, acc, 0, 0, 0);
  }
  int n = n0 + col;
  float bv = (n < Nreal) ? bias[n] : 0.f;
#pragma unroll
  for (int r = 0; r < 4; ++r) {
    int m = m0 + quad * 4 + r;
    float v = acc[r] + bv;
    if (ACT == 1) v = fmaxf(v, 0.f);
    if (ACT == 2) v = tanf_(v);
    size_t idx = (size_t)m * ldc + n;
    if (WB) Cb[idx] = (__bf16)v;
    if (WF) Cf[idx] = v;
  }
}

// transpose q_key (b*128+s, 112-ld) -> qkT[b][100][128] for coalesced energy
__global__ void transpose_qk(const float* __restrict__ q, float* __restrict__ qT) {
  int b = blockIdx.x;
  for (int i = threadIdx.x; i < 100 * 128; i += blockDim.x) {
    int k = i >> 7, s = i & 127;
    qT[((size_t)b * 100 + k) * 128 + s] = q[((size_t)b * 128 + s) * 112 + k];
  }
}

// ---------------------------------------------------------------------------
// Persistent encoder: 256 blocks (1/CU), weights in LDS, custom barrier.
// block bb: ug = bb>>1 (8 hidden units), mh = bb&1 (64 batch rows).
// ---------------------------------------------------------------------------
struct EncArgs {
  const __bf16* wE; const float* bEncF; const __bf16* embE;
  __bf16* h0; __bf16* h1; float* cE; const int* lens; __bf16* SH; unsigned* bar;
};

__global__ __launch_bounds__(256, 1)
void enc_coop(EncArgs a) {
  extern __shared__ char smem[];
  __bf16* Wl = (__bf16*)smem;                                        // 86016 B
  float* zb = (float*)(smem + 2 * KCE * 512 * 2);                    // 8448 B
  __bf16* hbuf = (__bf16*)(smem + 2 * KCE * 512 * 2 + 64 * 33 * 4);  // 1024 B
  const int bb = blockIdx.x;
  const int ug = bb >> 1, mh = bb & 1;
  {
    const uint4* src = (const uint4*)(a.wE + (size_t)ug * 2 * KCE * 512);
    uint4* dst = (uint4*)Wl;
    for (int i = threadIdx.x; i < 2 * KCE * 512 * 2 / 16; i += 256) dst[i] = src[i];
  }
  const int tid = threadIdx.x;
  const int lane = tid & 63, wave = tid >> 6;
  const int col = lane & 15, quad = lane >> 4, koff = quad * 8;
  const int am = mh * 64 + wave * 16 + col;
  __syncthreads();

  for (int t = 0; t < S_; ++t) {
    const __bf16* hR = (t & 1) ? a.h1 : a.h0;
    __bf16* hW = (t & 1) ? a.h0 : a.h1;
    f32x4 acc0 = {0.f, 0.f, 0.f, 0.f}, acc1 = {0.f, 0.f, 0.f, 0.f};
    const __bf16* embRow = a.embE + ((size_t)t * B_ + am) * 320 + koff;
    const ull* hRow8 = (const ull*)(hR + (size_t)am * H_) + quad * 2;
#pragma unroll
    for (int kc = 0; kc < KCE; ++kc) {
      const int k0 = kc * 32;
      bf16x8 af;
      if (k0 < 320) {
        af = *(const bf16x8*)(embRow + k0);
      } else {
        Pack8 u2;
        u2.q[0] = al8(hRow8 + ((k0 - 320) >> 2));
        u2.q[1] = al8(hRow8 + ((k0 - 320) >> 2) + 1);
        af = u2.v;
      }
      bf16x8 b0 = *(const bf16x8*)(Wl + ((size_t)(0 * KCE + kc) * 64 + lane) * 8);
      bf16x8 b1 = *(const bf16x8*)(Wl + ((size_t)(1 * KCE + kc) * 64 + lane) * 8);
      acc0 = __builtin_amdgcn_mfma_f32_16x16x32_bf16(af, b0, acc0, 0, 0, 0);
      acc1 = __builtin_amdgcn_mfma_f32_16x16x32_bf16(af, b1, acc1, 0, 0, 0);
    }
#pragma unroll
    for (int r = 0; r < 4; ++r) {
      int ml = wave * 16 + quad * 4 + r;
      zb[ml * 33 + col] = acc0[r];
      zb[ml * 33 + 16 + col] = acc1[r];
    }
    __syncthreads();
#pragma unroll
    for (int p = 0; p < 2; ++p) {
      int idx = tid + p * 256;
      int ml = idx >> 3, u = idx & 7;
      int m = mh * 64 + ml, j = ug * 8 + u;
      float ig = sigf(zb[ml * 33 + u]       + a.bEncF[j]);
      float fg = sigf(zb[ml * 33 + 8 + u]   + a.bEncF[1024 + j]);
      float gg = tanf_(zb[ml * 33 + 16 + u] + a.bEncF[2048 + j]);
      float og = sigf(zb[ml * 33 + 24 + u]  + a.bEncF[3072 + j]);
      size_t sidx = (size_t)m * H_ + j;
      float cOld = a.cE[sidx];
      float c2 = fg * cOld + ig * gg;
      float h2 = og * tanf_(c2);
      bool valid = t < a.lens[m];
      a.cE[sidx] = valid ? c2 : cOld;          // c is block-private: plain
      hbuf[ml * 8 + u] = (__bf16)h2;
      a.SH[((size_t)m * S_ + t) * H_ + j] = valid ? (__bf16)h2 : (__bf16)0.f;
    }
    __syncthreads();
    if (tid < 128) {   // publish h slice: 4 bf16 per 8B atomic store
      int ml = tid >> 1, u0 = (tid & 1) * 4;
      int m = mh * 64 + ml;
      ull nv = *(const ull*)(hbuf + ml * 8 + u0);
      if (t >= a.lens[m]) nv = al8((const ull*)(hR + (size_t)m * H_ + ug * 8 + u0));
      as8((ull*)(hW + (size_t)m * H_ + ug * 8 + u0), nv);
    }
    if (t != S_ - 1) gbar(a.bar, bb, t + 1);
  }
}

// ---------------------------------------------------------------------------
// Persistent decoder: per step, phase A = attention (blocks 0..127), barrier,
// phase B = LSTM (all blocks), barrier.
// ---------------------------------------------------------------------------
struct DecArgs {
  const __bf16* wD; const float* bDecF; const __bf16* ansP;
  __bf16* h0; __bf16* h1; float* cD; const int* lens;
  const __bf16* waB; const float* baF; const float* qkT; const float* qval;
  __bf16* ctx; void* out; const int* flag; unsigned* bar;
};

__global__ __launch_bounds__(256, 1)
void dec_coop(DecArgs a) {
  extern __shared__ char smem[];
  __bf16* Wl = (__bf16*)smem;                                        // 122880 B
  float* zb = (float*)(smem + 2 * KCD * 512 * 2);                    // 8448 B
  __bf16* hbuf = (__bf16*)(smem + 2 * KCD * 512 * 2 + 64 * 33 * 4);  // 1024 B
  const int bb = blockIdx.x;
  const int ug = bb >> 1, mh = bb & 1;
  {
    const uint4* src = (const uint4*)(a.wD + (size_t)ug * 2 * KCD * 512);
    uint4* dst = (uint4*)Wl;
    for (int i = threadIdx.x; i < 2 * KCD * 512 * 2 / 16; i += 256) dst[i] = src[i];
  }
  const int tid = threadIdx.x;
  const int lane = tid & 63, wave = tid >> 6;
  const int col = lane & 15, quad = lane >> 4, koff = quad * 8;
  const int am = mh * 64 + wave * 16 + col;
  const bool obf = *a.flag != 0;
  __syncthreads();

  for (int t = 0; t < T_; ++t) {
    const __bf16* hR = (t & 1) ? a.h1 : a.h0;
    __bf16* hW = (t & 1) ? a.h0 : a.h1;
    // ---- phase A: attention for b = bb ----
    if (bb < B_) {
      const int b = bb;
      float* ak = zb; float* wts = zb + 112; float* sc = zb + 240; float* ctxb = zb + 368;
      // h row in registers via bypass loads (fresh from coherence point)
      const ull* hp = (const ull*)(hR + (size_t)b * H_);
      Pack8 u0, u1;
      u0.q[0] = al8(hp + lane * 4 + 0); u0.q[1] = al8(hp + lane * 4 + 1);
      u1.q[0] = al8(hp + lane * 4 + 2); u1.q[1] = al8(hp + lane * 4 + 3);
      float hf[16];
#pragma unroll
      for (int j2 = 0; j2 < 8; ++j2) { hf[j2] = (float)u0.v[j2]; hf[8 + j2] = (float)u1.v[j2]; }
      for (int n = wave; n < 100; n += 4) {
        bf16x8 w0 = *(const bf16x8*)(a.waB + (size_t)n * 1024 + lane * 16);
        bf16x8 w1 = *(const bf16x8*)(a.waB + (size_t)n * 1024 + lane * 16 + 8);
        float acc = 0.f;
#pragma unroll
        for (int j2 = 0; j2 < 8; ++j2)
          acc += hf[j2] * (float)w0[j2] + hf[8 + j2] * (float)w1[j2];
#pragma unroll
        for (int off = 32; off > 0; off >>= 1) acc += __shfl_xor(acc, off);
        if (lane == 0) ak[n] = tanf_(acc + a.baF[n]);
      }
      __syncthreads();
      int len = a.lens[b];
      if (tid < S_) {
        float e = -1e30f;
        if (tid < len) {
          float acc = 0.f;
#pragma unroll 4
          for (int k = 0; k < 100; ++k)
            acc += a.qkT[((size_t)b * 100 + k) * 128 + tid] * ak[k];
          e = acc;
        }
        wts[tid] = e; sc[tid] = e;
      }
      __syncthreads();
      for (int off = 64; off > 0; off >>= 1) {
        if (tid < off) sc[tid] = fmaxf(sc[tid], sc[tid + off]);
        __syncthreads();
      }
      float mx = sc[0];
      __syncthreads();
      if (tid < S_) {
        float ex = (wts[tid] <= -1e29f) ? 0.f : __expf(wts[tid] - mx);
        wts[tid] = ex; sc[tid] = ex;
      }
      __syncthreads();
      for (int off = 64; off > 0; off >>= 1) {
        if (tid < off) sc[tid] += sc[tid + off];
        __syncthreads();
      }
      float inv = 1.f / sc[0];
      for (int d = tid; d < 320; d += 256) {
        float v = 0.f;
        if (d < 300) {
#pragma unroll 8
          for (int s = 0; s < S_; ++s) v += wts[s] * a.qval[((size_t)b * S_ + s) * 304 + d];
          v *= inv;
        }
        ctxb[d] = v;
      }
      __syncthreads();
      if (tid < 80) {   // publish ctx row: 4 bf16 per 8B atomic store
        __bf16 p4[4];
#pragma unroll
        for (int i2 = 0; i2 < 4; ++i2) p4[i2] = (__bf16)ctxb[tid * 4 + i2];
        as8((ull*)a.ctx + (size_t)b * 80 + tid, *(const ull*)p4);
      }
    }
    gbar(a.bar, bb, 2 * t + 1);
    // ---- phase B: LSTM step (all blocks) ----
    f32x4 acc0 = {0.f, 0.f, 0.f, 0.f}, acc1 = {0.f, 0.f, 0.f, 0.f};
    const __bf16* ansRow = a.ansP + ((size_t)t * B_ + am) * 576 + koff;
    const ull* ctxRow8 = (const ull*)a.ctx + (size_t)am * 80 + quad * 2;
    const ull* hRow8 = (const ull*)(hR + (size_t)am * H_) + quad * 2;
#pragma unroll
    for (int kc = 0; kc < KCD; ++kc) {
      const int k0 = kc * 32;
      bf16x8 af;
      if (k0 < 576) {
        af = *(const bf16x8*)(ansRow + k0);
      } else if (k0 < 896) {
        Pack8 u2;
        u2.q[0] = al8(ctxRow8 + ((k0 - 576) >> 2));
        u2.q[1] = al8(ctxRow8 + ((k0 - 576) >> 2) + 1);
        af = u2.v;
      } else {
        Pack8 u2;
        u2.q[0] = al8(hRow8 + ((k0 - 896) >> 2));
        u2.q[1] = al8(hRow8 + ((k0 - 896) >> 2) + 1);
        af = u2.v;
      }
      bf16x8 b0 = *(const bf16x8*)(Wl + ((size_t)(0 * KCD + kc) * 64 + lane) * 8);
      bf16x8 b1 = *(const bf16x8*)(Wl + ((size_t)(1 * KCD + kc) * 64 + lane) * 8);
      acc0 = __builtin_amdgcn_mfma_f32_16x16x32_bf16(af, b0, acc0, 0, 0, 0);
      acc1 = __builtin_amdgcn_mfma_f32_16x16x32_bf16(af, b1, acc1, 0, 0, 0);
    }
#pragma unroll
    for (int r = 0; r < 4; ++r) {
      int ml = wave * 16 + quad * 4 + r;
      zb[ml * 33 + col] = acc0[r];
      zb[ml * 33 + 16 + col] = acc1[r];
    }
    __syncthreads();
#pragma unroll
    for (int p = 0; p < 2; ++p) {
      int idx = tid + p * 256;
      int ml = idx >> 3, u = idx & 7;
      int m = mh * 64 + ml, j = ug * 8 + u;
      float ig = sigf(zb[ml * 33 + u]       + a.bDecF[j]);
      float fg = sigf(zb[ml * 33 + 8 + u]   + a.bDecF[1024 + j]);
      float gg = tanf_(zb[ml * 33 + 16 + u] + a.bDecF[2048 + j]);
      float og = sigf(zb[ml * 33 + 24 + u]  + a.bDecF[3072 + j]);
      size_t sidx = (size_t)m * H_ + j;
      float cOld = a.cD[sidx];
      float c2 = fg * cOld + ig * gg;
      float h2 = og * tanf_(c2);
      a.cD[sidx] = c2;                          // block-private: plain
      hbuf[ml * 8 + u] = (__bf16)h2;
      size_t oidx = ((size_t)m * T_ + t) * H_ + j;
      if (obf) ((__bf16*)a.out)[oidx] = (__bf16)h2;
      else     ((float*)a.out)[oidx] = h2;
    }
    __syncthreads();
    if (tid < 128) {   // publish h slice
      int ml = tid >> 1, u0 = (tid & 1) * 4;
      int m = mh * 64 + ml;
      ull nv = *(const ull*)(hbuf + ml * 8 + u0);
      as8((ull*)(hW + (size_t)m * H_ + ug * 8 + u0), nv);
    }
    if (t != T_ - 1) gbar(a.bar, bb, 2 * t + 2);
  }
}

// ---------------------------------------------------------------------------
extern "C" void kernel_launch(void* const* d_in, const int* in_sizes, int n_in,
                              void* d_out, int out_size, void* d_ws, size_t ws_size,
                              hipStream_t stream) {
  const int* src_seqs = (const int*)d_in[0];
  const int* src_len  = (const int*)d_in[1];
  const int* trg_nt   = (const int*)d_in[2];
  const int* par_nt   = (const int*)d_in[3];
  const int* par_lex  = (const int*)d_in[4];
  const void* lex_emb = d_in[5];
  const void* nt_emb  = d_in[6];
  const void* encWih  = d_in[7];
  const void* encWhh  = d_in[8];
  const void* encB    = d_in[9];
  const void* decWih  = d_in[10];
  const void* decWhh  = d_in[11];
  const void* decB    = d_in[12];
  const void* Wh1 = d_in[13]; const void* bh1 = d_in[14];
  const void* Wh2 = d_in[15]; const void* bh2 = d_in[16];
  const void* Wc1 = d_in[17]; const void* bc1 = d_in[18];
  const void* Wc2 = d_in[19]; const void* bc2 = d_in[20];
  const void* Wa  = d_in[21]; const void* ba  = d_in[22];
  const void* Wqk = d_in[23]; const void* bqk = d_in[24];
  const void* Wqv = d_in[25]; const void* bqv = d_in[26];

  char* base = (char*)d_ws;
  size_t off = 0;
  auto alloc = [&](size_t bytes) -> char* {
    char* p = base + off;
    off += (bytes + 255) & ~(size_t)255;
    return p;
  };
  __bf16* wEnc = (__bf16*)alloc((size_t)4096 * KE_ * 2);
  float*  bEncF = (float*)alloc(4096 * 4);
  __bf16* wDec = (__bf16*)alloc((size_t)4096 * KD_ * 2);
  float*  bDecF = (float*)alloc(4096 * 4);
  __bf16* embE = (__bf16*)alloc((size_t)S_ * B_ * 320 * 2);
  __bf16* ansP = (__bf16*)alloc((size_t)T_ * B_ * 576 * 2);
  __bf16* SH   = (__bf16*)alloc((size_t)B_ * S_ * H_ * 2);
  __bf16* wh1p = (__bf16*)alloc((size_t)2048 * 1024 * 2);
  __bf16* wh2p = (__bf16*)alloc((size_t)1024 * 2048 * 2);
  __bf16* wc1p = (__bf16*)alloc((size_t)2048 * 1024 * 2);
  __bf16* wc2p = (__bf16*)alloc((size_t)1024 * 2048 * 2);
  __bf16* wqkp = (__bf16*)alloc((size_t)112 * 1024 * 2);
  __bf16* wqvp = (__bf16*)alloc((size_t)304 * 1024 * 2);
  __bf16* waB  = (__bf16*)alloc((size_t)112 * 1024 * 2);
  float*  qkey = (float*)alloc((size_t)B_ * S_ * 112 * 4);
  float*  qkT  = (float*)alloc((size_t)B_ * 100 * 128 * 4);
  float*  qval = (float*)alloc((size_t)B_ * S_ * 304 * 4);
  __bf16* hE0 = (__bf16*)alloc((size_t)B_ * H_ * 2);
  __bf16* hE1 = (__bf16*)alloc((size_t)B_ * H_ * 2);
  float*  cE  = (float*)alloc((size_t)B_ * H_ * 4);
  __bf16* cEb = (__bf16*)alloc((size_t)B_ * H_ * 2);
  __bf16* t1b = (__bf16*)alloc((size_t)B_ * 2048 * 2);
  __bf16* t2b = (__bf16*)alloc((size_t)B_ * 2048 * 2);
  __bf16* hD0 = (__bf16*)alloc((size_t)B_ * H_ * 2);
  __bf16* hD1 = (__bf16*)alloc((size_t)B_ * H_ * 2);
  float*  cD  = (float*)alloc((size_t)B_ * H_ * 4);
  __bf16* ctx = (__bf16*)alloc((size_t)B_ * 320 * 2);
  float*  bh1F = (float*)alloc(2048 * 4);
  float*  bh2F = (float*)alloc(1024 * 4);
  float*  bc1F = (float*)alloc(2048 * 4);
  float*  bc2F = (float*)alloc(1024 * 4);
  float*  baF  = (float*)alloc(112 * 4);
  float*  bqkF = (float*)alloc(112 * 4);
  float*  bqvF = (float*)alloc(304 * 4);
  unsigned* bar = (unsigned*)alloc(1024 * 4);   // enc: [0..511], dec: [512..1023]
  int*    flag = (int*)alloc(256);
  if (off > ws_size) return;

  // ---- prep ----
  sniff<<<1, 64, 0, stream>>>(lex_emb, flag);
  zero_bar<<<1, 1024, 0, stream>>>(bar);
  cvt_to_f32<<<16, 256, 0, stream>>>(encB, bEncF, 4096, flag);
  cvt_to_f32<<<16, 256, 0, stream>>>(decB, bDecF, 4096, flag);
  cvt_to_f32<<<8, 256, 0, stream>>>(bh1, bh1F, 2048, flag);
  cvt_to_f32<<<4, 256, 0, stream>>>(bh2, bh2F, 1024, flag);
  cvt_to_f32<<<8, 256, 0, stream>>>(bc1, bc1F, 2048, flag);
  cvt_to_f32<<<4, 256, 0, stream>>>(bc2, bc2F, 1024, flag);
  cvt_to_f32<<<1, 256, 0, stream>>>(ba, baF, 100, flag);
  cvt_to_f32<<<1, 256, 0, stream>>>(bqk, bqkF, 100, flag);
  cvt_to_f32<<<2, 256, 0, stream>>>(bqv, bqvF, 300, flag);
  build_w_enc_sw<<<256, 512, 0, stream>>>(encWih, encWhh, wEnc, flag);
  build_w_dec_sw<<<256, 512, 0, stream>>>(decWih, decWhh, wDec, flag);
  pad_cvt<<<2048, 256, 0, stream>>>(Wh1, wh1p, 2048, 1024, 1024, flag);
  pad_cvt<<<1024, 256, 0, stream>>>(Wh2, wh2p, 1024, 2048, 2048, flag);
  pad_cvt<<<2048, 256, 0, stream>>>(Wc1, wc1p, 2048, 1024, 1024, flag);
  pad_cvt<<<1024, 256, 0, stream>>>(Wc2, wc2p, 1024, 2048, 2048, flag);
  pad_cvt<<<112, 256, 0, stream>>>(Wqk, wqkp, 100, 1024, 1024, flag);
  pad_cvt<<<304, 256, 0, stream>>>(Wqv, wqvp, 300, 1024, 1024, flag);
  pad_cvt<<<100, 256, 0, stream>>>(Wa, waB, 100, 1024, 1024, flag);
  gather_emb<<<S_ * B_, 256, 0, stream>>>(lex_emb, src_seqs, embE, flag);
  gather_ans<<<T_ * B_, 256, 0, stream>>>(nt_emb, lex_emb, trg_nt, par_nt, par_lex, ansP, flag);
  zero_state<<<512, 256, 0, stream>>>(hE0, cE);

  const unsigned encLds = 2 * KCE * 512 * 2 + 64 * 33 * 4 + 1024;   // 95488 B
  const unsigned decLds = 2 * KCD * 512 * 2 + 64 * 33 * 4 + 1024;   // 132352 B
  hipFuncSetAttribute((const void*)enc_coop, hipFuncAttributeMaxDynamicSharedMemorySize, encLds);
  hipFuncSetAttribute((const void*)dec_coop, hipFuncAttributeMaxDynamicSharedMemorySize, decLds);

  // ---- encoder: one launch, 128 steps ----
  EncArgs ea = {wEnc, bEncF, embE, hE0, hE1, cE, src_len, SH, bar};
  void* eargs[] = {&ea};
  hipLaunchCooperativeKernel((const void*)enc_coop, dim3(256), dim3(256), eargs, encLds, stream);

  // ---- decoder init MLPs (final enc state in hE0 / cE) ----
  f2b<<<512, 256, 0, stream>>>(cE, cEb, B_ * H_);
  gemm16<1, true, false><<<dim3(128, 2), 256, 0, stream>>>(hE0, 1024, wh1p, 1024, bh1F, 2048, t1b, nullptr, 2048);
  gemm16<0, true, false><<<dim3(64, 2), 256, 0, stream>>>(t1b, 2048, wh2p, 2048, bh2F, 1024, hD0, nullptr, 1024);
  gemm16<1, true, false><<<dim3(128, 2), 256, 0, stream>>>(cEb, 1024, wc1p, 1024, bc1F, 2048, t2b, nullptr, 2048);
  gemm16<0, false, true><<<dim3(64, 2), 256, 0, stream>>>(t2b, 2048, wc2p, 2048, bc2F, 1024, nullptr, cD, 1024);

  // ---- attention keys/values over all (b,s) ----
  gemm16<2, false, true><<<dim3(7, 256), 256, 0, stream>>>(SH, 1024, wqkp, 1024, bqkF, 100, nullptr, qkey, 112);
  transpose_qk<<<B_, 256, 0, stream>>>(qkey, qkT);
  gemm16<0, false, true><<<dim3(19, 256), 256, 0, stream>>>(SH, 1024, wqvp, 1024, bqvF, 300, nullptr, qval, 304);

  // ---- decoder: one launch, 64 steps w/ in-kernel attention ----
  DecArgs da = {wDec, bDecF, ansP, hD0, hD1, cD, src_len,
                waB, baF, qkT, qval, ctx, d_out, flag, bar + 512};
  void* dargs[] = {&da};
  hipLaunchCooperativeKernel((const void*)dec_coop, dim3(256), dim3(256), dargs, decLds, stream);
}

// Round 4
// 4761.548 us; speedup vs baseline: 3.5093x; 1.1920x over previous
//
#include <hip/hip_runtime.h>

// ---------------------------------------------------------------------------
// LexicalizedGrammarDecoder — weight-stationary persistent kernels with a
// fence-free grid barrier, ONE barrier per LSTM step, and software pipelining
// (input-dependent K-segment of step t+1 computed inside the barrier window;
// output stores deferred past the arrival). ctx dependency in the decoder is
// per-row epoch flags instead of a second barrier.
// ---------------------------------------------------------------------------

constexpr int B_ = 128, S_ = 128, T_ = 64, H_ = 1024;
constexpr int KE_ = 1344;  // enc step K: 320 (emb pad) + 1024 (h)
constexpr int KD_ = 1920;  // dec step K: 576 (ans pad) + 320 (ctx pad) + 1024 (h)
constexpr int KCE = KE_ / 32, KCD = KD_ / 32;   // 42, 60

using bf16x8 = __attribute__((ext_vector_type(8))) __bf16;
using f32x4  = __attribute__((ext_vector_type(4))) float;
using ull = unsigned long long;

union Pack8 { ull q[2]; bf16x8 v; };
union Pack4 { __bf16 h[4]; ull q; };

__device__ __forceinline__ float ldf(const void* p, size_t i, bool bf) {
  return bf ? (float)((const __bf16*)p)[i] : ((const float*)p)[i];
}
__device__ __forceinline__ float sigf(float x) { return 1.f / (1.f + __expf(-x)); }
__device__ __forceinline__ float tanf_(float x) { return 1.f - 2.f / (1.f + __expf(2.f * x)); }

__device__ __forceinline__ ull al8(const ull* p) {
  return __hip_atomic_load(p, __ATOMIC_RELAXED, __HIP_MEMORY_SCOPE_AGENT);
}
__device__ __forceinline__ void as8(ull* p, ull v) {
  __hip_atomic_store(p, v, __ATOMIC_RELAXED, __HIP_MEMORY_SCOPE_AGENT);
}
__device__ __forceinline__ unsigned alu(const unsigned* p) {
  return __hip_atomic_load(p, __ATOMIC_RELAXED, __HIP_MEMORY_SCOPE_AGENT);
}
__device__ __forceinline__ void asu(unsigned* p, unsigned v) {
  __hip_atomic_store(p, v, __ATOMIC_RELAXED, __HIP_MEMORY_SCOPE_AGENT);
}

// barrier split: caller does __syncthreads() (drains publish stores) first.
__device__ __forceinline__ void garrive(unsigned* slots, int bb) {
  if (threadIdx.x == 0)
    __hip_atomic_fetch_add(&slots[(bb & 31) * 32], 1u, __ATOMIC_RELAXED,
                           __HIP_MEMORY_SCOPE_AGENT);
}
__device__ __forceinline__ void gwait(unsigned* slots, unsigned tgt) {
  if (threadIdx.x < 32) {
    while (alu(&slots[threadIdx.x * 32]) < tgt) __builtin_amdgcn_s_sleep(1);
  }
  __syncthreads();
}

// --- dtype sniffer ----------------------------------------------------------
__global__ void sniff(const void* __restrict__ lex, int* __restrict__ flag) {
  if (threadIdx.x == 0 && blockIdx.x == 0) {
    const unsigned short* u = (const unsigned short*)lex;
    int garbage = 0;
    for (int i = 0; i < 64; ++i) {
      unsigned short v = u[1000000 + 2 * i];
      int ex = (v >> 7) & 0xFF;
      bool sane = ((v & 0x7FFF) == 0) || (ex >= 107 && ex <= 147);
      if (!sane) ++garbage;
    }
    *flag = (garbage >= 16) ? 0 : 1;  // 1 => inputs are bf16
  }
}

__global__ void cvt_to_f32(const void* __restrict__ src, float* __restrict__ dst,
                           int n, const int* __restrict__ flag) {
  int i = blockIdx.x * blockDim.x + threadIdx.x;
  bool bf = *flag != 0;
  if (i < n) dst[i] = ldf(src, i, bf);
}

__global__ void f2b(const float* __restrict__ s, __bf16* __restrict__ d, int n) {
  int i = blockIdx.x * blockDim.x + threadIdx.x;
  if (i < n) d[i] = (__bf16)s[i];
}

__global__ void zero_state(__bf16* __restrict__ h, float* __restrict__ c) {
  int i = blockIdx.x * blockDim.x + threadIdx.x;
  if (i < B_ * H_) { h[i] = (__bf16)0.f; c[i] = 0.f; }
}

__global__ void zero_bar(unsigned* __restrict__ bar) {
  int i = blockIdx.x * blockDim.x + threadIdx.x;
  if (i < 2304) bar[i] = 0u;
}

// --- swizzled step-weight builders (verified R1-R3) -------------------------
// dst: [ug(128)][nt(2)][kc][lane(64)][8] bf16 = per-lane MFMA B-fragment order.
__global__ void build_w_enc_sw(const void* __restrict__ Wih, const void* __restrict__ Whh,
                               __bf16* __restrict__ W, const int* __restrict__ flag) {
  int bid = blockIdx.x;            // 256 = ug*2 + nt
  int ug = bid >> 1, nt = bid & 1;
  bool bf = *flag != 0;
  for (int i = threadIdx.x; i < KCE * 512; i += blockDim.x) {
    int kc = i >> 9, rem = i & 511, lane = rem >> 3, j = rem & 7;
    int col = lane & 15, quad = lane >> 4;
    int gate = nt * 2 + (col >> 3), ul = col & 7;
    int r = gate * 1024 + ug * 8 + ul;
    int k = kc * 32 + quad * 8 + j;
    float v;
    if (k < 320) v = (k < 300) ? ldf(Wih, (size_t)r * 300 + k, bf) : 0.f;
    else         v = ldf(Whh, (size_t)r * 1024 + (k - 320), bf);
    W[(((size_t)bid * KCE + kc) * 64 + lane) * 8 + j] = (__bf16)v;
  }
}

__global__ void build_w_dec_sw(const void* __restrict__ Wih, const void* __restrict__ Whh,
                               __bf16* __restrict__ W, const int* __restrict__ flag) {
  int bid = blockIdx.x;
  int ug = bid >> 1, nt = bid & 1;
  bool bf = *flag != 0;
  for (int i = threadIdx.x; i < KCD * 512; i += blockDim.x) {
    int kc = i >> 9, rem = i & 511, lane = rem >> 3, j = rem & 7;
    int col = lane & 15, quad = lane >> 4;
    int gate = nt * 2 + (col >> 3), ul = col & 7;
    int r = gate * 1024 + ug * 8 + ul;
    int k = kc * 32 + quad * 8 + j;
    float v;
    if (k < 576)      v = (k < 556) ? ldf(Wih, (size_t)r * 856 + k, bf) : 0.f;
    else if (k < 896) { int kk = k - 576; v = (kk < 300) ? ldf(Wih, (size_t)r * 856 + 556 + kk, bf) : 0.f; }
    else              v = ldf(Whh, (size_t)r * 1024 + (k - 896), bf);
    W[(((size_t)bid * KCD + kc) * 64 + lane) * 8 + j] = (__bf16)v;
  }
}

__global__ void pad_cvt(const void* __restrict__ src, __bf16* __restrict__ dst,
                        int N, int K, int Kpad, const int* __restrict__ flag) {
  int n = blockIdx.x;
  bool bf = *flag != 0;
  for (int k = threadIdx.x; k < Kpad; k += blockDim.x) {
    float v = (n < N && k < K) ? ldf(src, (size_t)n * K + k, bf) : 0.f;
    dst[(size_t)n * Kpad + k] = (__bf16)v;
  }
}

// --- embedding gathers ------------------------------------------------------
__global__ void gather_emb(const void* __restrict__ lex, const int* __restrict__ seq,
                           __bf16* __restrict__ dst, const int* __restrict__ flag) {
  int blk = blockIdx.x;          // blk = t*B + b
  int t = blk >> 7, b = blk & 127;
  int id = seq[b * S_ + t];
  bool bf = *flag != 0;
  for (int k = threadIdx.x; k < 320; k += blockDim.x) {
    float v = (k < 300) ? ldf(lex, (size_t)id * 300 + k, bf) : 0.f;
    dst[(size_t)blk * 320 + k] = (__bf16)v;
  }
}

__global__ void gather_ans(const void* __restrict__ nt, const void* __restrict__ lex,
                           const int* __restrict__ trg, const int* __restrict__ par,
                           const int* __restrict__ plex, __bf16* __restrict__ dst,
                           const int* __restrict__ flag) {
  int blk = blockIdx.x;          // blk = t*B + b
  int t = blk >> 7, b = blk & 127;
  int i1 = trg[b * T_ + t], i2 = par[b * T_ + t], i3 = plex[b * T_ + t];
  bool bf = *flag != 0;
  for (int k = threadIdx.x; k < 576; k += blockDim.x) {
    float v = 0.f;
    if (k < 128)      v = ldf(nt, (size_t)i1 * 128 + k, bf);
    else if (k < 256) v = ldf(nt, (size_t)i2 * 128 + (k - 128), bf);
    else if (k < 556) v = ldf(lex, (size_t)i3 * 300 + (k - 256), bf);
    dst[(size_t)blk * 576 + k] = (__bf16)v;
  }
}

// --- generic GEMM: C = act(A @ W^T + bias) ----------------------------------
// OM=0: C[m][ldc]+n.  OM=1: transposed C[(b*ldc+n)*128+s] with m = s*128+b.
template <int ACT, bool WB, bool WF, int OM>
__global__ __launch_bounds__(256)
void gemm16(const __bf16* __restrict__ A, int lda,
            const __bf16* __restrict__ W, int K,
            const float* __restrict__ bias, int Nreal,
            __bf16* __restrict__ Cb, float* __restrict__ Cf, int ldc) {
  const int lane = threadIdx.x & 63;
  const int wave = threadIdx.x >> 6;
  const int col = lane & 15, quad = lane >> 4, koff = quad * 8;
  const int n0 = blockIdx.x * 16;
  const int m0 = blockIdx.y * 64 + wave * 16;
  f32x4 acc = {0.f, 0.f, 0.f, 0.f};
  const __bf16* ap = A + (size_t)(m0 + col) * lda + koff;
  const __bf16* wp = W + (size_t)(n0 + col) * K + koff;
  for (int k0 = 0; k0 < K; k0 += 32) {
    bf16x8 af = *(const bf16x8*)(ap + k0);
    bf16x8 bf = *(const bf16x8*)(wp + k0);
    acc = __builtin_amdgcn_mfma_f32_16x16x32_bf16(af, bf, acc, 0, 0, 0);
  }
  int n = n0 + col;
  float bv = (n < Nreal) ? bias[n] : 0.f;
#pragma unroll
  for (int r = 0; r < 4; ++r) {
    int m = m0 + quad * 4 + r;
    float v = acc[r] + bv;
    if (ACT == 1) v = fmaxf(v, 0.f);
    if (ACT == 2) v = tanf_(v);
    size_t idx;
    if (OM == 0) idx = (size_t)m * ldc + n;
    else         idx = ((size_t)(m & 127) * ldc + n) * 128 + (m >> 7);
    if (WB) Cb[idx] = (__bf16)v;
    if (WF) Cf[idx] = v;
  }
}

// ---------------------------------------------------------------------------
// Persistent encoder. block bb: ug = bb>>1 (8 units), mh = bb&1 (64 rows).
// ---------------------------------------------------------------------------
struct EncArgs {
  const __bf16* wE; const float* bEncF; const __bf16* embE;
  __bf16* h0; __bf16* h1; float* cE; const int* lens; __bf16* SH; unsigned* bar;
};

__global__ __launch_bounds__(256, 1)
void enc_coop(EncArgs a) {
  extern __shared__ char smem[];
  __bf16* Wl = (__bf16*)smem;                                        // 86016 B
  float* zb = (float*)(smem + 2 * KCE * 512 * 2);                    // 8448 B
  __bf16* hbuf = (__bf16*)(smem + 2 * KCE * 512 * 2 + 64 * 33 * 4);  // 1024 B
  const int bb = blockIdx.x;
  const int ug = bb >> 1, mh = bb & 1;
  {
    const uint4* src = (const uint4*)(a.wE + (size_t)ug * 2 * KCE * 512);
    uint4* dst = (uint4*)Wl;
    for (int i = threadIdx.x; i < 2 * KCE * 512 * 2 / 16; i += 256) dst[i] = src[i];
  }
  const int tid = threadIdx.x;
  const int lane = tid & 63, wave = tid >> 6;
  const int col = lane & 15, quad = lane >> 4, koff = quad * 8;
  const int am = mh * 64 + wave * 16 + col;
  // epilogue preloads
  const int e_u = tid & 7;
  const int jj = ug * 8 + e_u;
  const float bi = a.bEncF[jj], bff = a.bEncF[1024 + jj];
  const float bg = a.bEncF[2048 + jj], bo = a.bEncF[3072 + jj];
  const int m0p = mh * 64 + (tid >> 3);           // p0 row
  const int len0 = a.lens[m0p], len1 = a.lens[m0p + 32];
  const int pm = mh * 64 + (tid >> 1);            // publish row (tid<128)
  const int slen = (tid < 64) ? a.lens[mh * 64 + tid] : 0;
  ull lastpub = 0;
  __syncthreads();

  // pre-compute emb part for t=0
  f32x4 acc0 = {0.f, 0.f, 0.f, 0.f}, acc1 = {0.f, 0.f, 0.f, 0.f};
  {
    const __bf16* eRow = a.embE + (size_t)am * 320 + koff;
#pragma unroll
    for (int kc = 0; kc < 10; ++kc) {
      bf16x8 af = *(const bf16x8*)(eRow + kc * 32);
      bf16x8 b0 = *(const bf16x8*)(Wl + ((size_t)(0 * KCE + kc) * 64 + lane) * 8);
      bf16x8 b1 = *(const bf16x8*)(Wl + ((size_t)(1 * KCE + kc) * 64 + lane) * 8);
      acc0 = __builtin_amdgcn_mfma_f32_16x16x32_bf16(af, b0, acc0, 0, 0, 0);
      acc1 = __builtin_amdgcn_mfma_f32_16x16x32_bf16(af, b1, acc1, 0, 0, 0);
    }
  }

  for (int t = 0; t < S_; ++t) {
    const __bf16* hR = (t & 1) ? a.h1 : a.h0;
    __bf16* hW = (t & 1) ? a.h0 : a.h1;
    // h part (bypass loads)
    const ull* hRow8 = (const ull*)(hR + (size_t)am * H_) + quad * 2;
#pragma unroll
    for (int kc = 10; kc < KCE; ++kc) {
      Pack8 u2;
      u2.q[0] = al8(hRow8 + (kc * 8 - 80));
      u2.q[1] = al8(hRow8 + (kc * 8 - 80) + 1);
      bf16x8 b0 = *(const bf16x8*)(Wl + ((size_t)(0 * KCE + kc) * 64 + lane) * 8);
      bf16x8 b1 = *(const bf16x8*)(Wl + ((size_t)(1 * KCE + kc) * 64 + lane) * 8);
      acc0 = __builtin_amdgcn_mfma_f32_16x16x32_bf16(u2.v, b0, acc0, 0, 0, 0);
      acc1 = __builtin_amdgcn_mfma_f32_16x16x32_bf16(u2.v, b1, acc1, 0, 0, 0);
    }
#pragma unroll
    for (int r = 0; r < 4; ++r) {
      int ml = wave * 16 + quad * 4 + r;
      zb[ml * 33 + col] = acc0[r];
      zb[ml * 33 + 16 + col] = acc1[r];
    }
    __syncthreads();
#pragma unroll
    for (int p = 0; p < 2; ++p) {
      int ml = (tid >> 3) + p * 32;
      int m = mh * 64 + ml;
      int len = p ? len1 : len0;
      float ig = sigf(zb[ml * 33 + e_u] + bi);
      float fg = sigf(zb[ml * 33 + 8 + e_u] + bff);
      float gg = tanf_(zb[ml * 33 + 16 + e_u] + bg);
      float og = sigf(zb[ml * 33 + 24 + e_u] + bo);
      size_t sidx = (size_t)m * H_ + jj;
      float cOld = a.cE[sidx];
      float c2 = fg * cOld + ig * gg;
      float h2 = og * tanf_(c2);
      bool valid = t < len;
      a.cE[sidx] = valid ? c2 : cOld;
      hbuf[ml * 8 + e_u] = (__bf16)h2;
    }
    __syncthreads();
    if (tid < 128) {   // publish h(t+1): 8B bypass stores, lastpub for frozen rows
      ull nv = (t < ((tid & 1) ? a.lens[pm] : a.lens[pm])) ? ((const ull*)hbuf)[tid] : lastpub;
      // note: a.lens[pm] is L1/L2-hot scalar; keep simple
      lastpub = nv;
      as8((ull*)(hW + (size_t)pm * H_ + ug * 8) + (tid & 1), nv);
    }
    __syncthreads();   // drain publish before arrival
    garrive(a.bar, bb);
    // deferred: SH store (vector, masked)
    if (tid < 64) {
      int m = mh * 64 + tid;
      uint4 val;
      if (t < slen) val = *(const uint4*)(hbuf + tid * 8);
      else { val.x = 0; val.y = 0; val.z = 0; val.w = 0; }
      *(uint4*)(a.SH + ((size_t)t * B_ + m) * H_ + ug * 8) = val;
    }
    if (t != S_ - 1) {
      // pre-compute emb part for t+1
      acc0 = f32x4{0.f, 0.f, 0.f, 0.f}; acc1 = acc0;
      const __bf16* eRow = a.embE + ((size_t)(t + 1) * B_ + am) * 320 + koff;
#pragma unroll
      for (int kc = 0; kc < 10; ++kc) {
        bf16x8 af = *(const bf16x8*)(eRow + kc * 32);
        bf16x8 b0 = *(const bf16x8*)(Wl + ((size_t)(0 * KCE + kc) * 64 + lane) * 8);
        bf16x8 b1 = *(const bf16x8*)(Wl + ((size_t)(1 * KCE + kc) * 64 + lane) * 8);
        acc0 = __builtin_amdgcn_mfma_f32_16x16x32_bf16(af, b0, acc0, 0, 0, 0);
        acc1 = __builtin_amdgcn_mfma_f32_16x16x32_bf16(af, b1, acc1, 0, 0, 0);
      }
      gwait(a.bar, 8u * (unsigned)(t + 1));
    }
  }
}

// ---------------------------------------------------------------------------
// Persistent decoder: one barrier per step; ctx via per-row epoch flags.
// ---------------------------------------------------------------------------
struct DecArgs {
  const __bf16* wD; const float* bDecF; const __bf16* ansP;
  __bf16* h0; __bf16* h1; float* cD; const int* lens;
  const __bf16* waB; const float* baF; const float* qkT; const float* qvT;
  __bf16* ctx; void* out; const int* flag; unsigned* bar; unsigned* ctxFlag;
};

__global__ __launch_bounds__(256, 1)
void dec_coop(DecArgs a) {
  extern __shared__ char smem[];
  __bf16* Wl = (__bf16*)smem;                                        // 122880 B
  float* zb = (float*)(smem + 2 * KCD * 512 * 2);                    // 8448 B
  __bf16* hbuf = (__bf16*)(smem + 2 * KCD * 512 * 2 + 64 * 33 * 4);  // 1024 B
  const int bb = blockIdx.x;
  const int ug = bb >> 1, mh = bb & 1;
  {
    const uint4* src = (const uint4*)(a.wD + (size_t)ug * 2 * KCD * 512);
    uint4* dst = (uint4*)Wl;
    for (int i = threadIdx.x; i < 2 * KCD * 512 * 2 / 16; i += 256) dst[i] = src[i];
  }
  const int tid = threadIdx.x;
  const int lane = tid & 63, wave = tid >> 6;
  const int col = lane & 15, quad = lane >> 4, koff = quad * 8;
  const int am = mh * 64 + wave * 16 + col;
  const int m0w = mh * 64 + wave * 16;
  const bool obf = *a.flag != 0;
  const int e_u = tid & 7;
  const int jj = ug * 8 + e_u;
  const float bi = a.bDecF[jj], bff = a.bDecF[1024 + jj];
  const float bg = a.bDecF[2048 + jj], bo = a.bDecF[3072 + jj];
  const int pm = mh * 64 + (tid >> 1);
  const int alen = (bb < B_) ? a.lens[bb] : 0;
  __syncthreads();

  // pre-compute ans part for t=0
  f32x4 acc0 = {0.f, 0.f, 0.f, 0.f}, acc1 = {0.f, 0.f, 0.f, 0.f};
  {
    const __bf16* aRow = a.ansP + (size_t)am * 576 + koff;
#pragma unroll
    for (int kc = 0; kc < 18; ++kc) {
      bf16x8 af = *(const bf16x8*)(aRow + kc * 32);
      bf16x8 b0 = *(const bf16x8*)(Wl + ((size_t)(0 * KCD + kc) * 64 + lane) * 8);
      bf16x8 b1 = *(const bf16x8*)(Wl + ((size_t)(1 * KCD + kc) * 64 + lane) * 8);
      acc0 = __builtin_amdgcn_mfma_f32_16x16x32_bf16(af, b0, acc0, 0, 0, 0);
      acc1 = __builtin_amdgcn_mfma_f32_16x16x32_bf16(af, b1, acc1, 0, 0, 0);
    }
  }

  for (int t = 0; t < T_; ++t) {
    const __bf16* hR = (t & 1) ? a.h1 : a.h0;
    __bf16* hW = (t & 1) ? a.h0 : a.h1;
    // ---- attention for b = bb (blocks 0..127) ----
    if (bb < B_) {
      const int b = bb;
      float* ak = zb;           // 112
      float* wts = zb + 112;    // 128
      float* red = zb + 240;    // 8
      float* ctxb = zb + 256;   // 320
      const ull* hp = (const ull*)(hR + (size_t)b * H_);
      Pack8 u0, u1;
      u0.q[0] = al8(hp + lane * 4 + 0); u0.q[1] = al8(hp + lane * 4 + 1);
      u1.q[0] = al8(hp + lane * 4 + 2); u1.q[1] = al8(hp + lane * 4 + 3);
      float hf[16];
#pragma unroll
      for (int j2 = 0; j2 < 8; ++j2) { hf[j2] = (float)u0.v[j2]; hf[8 + j2] = (float)u1.v[j2]; }
      for (int n = wave; n < 100; n += 4) {
        bf16x8 w0 = *(const bf16x8*)(a.waB + (size_t)n * 1024 + lane * 16);
        bf16x8 w1 = *(const bf16x8*)(a.waB + (size_t)n * 1024 + lane * 16 + 8);
        float acc = 0.f;
#pragma unroll
        for (int j2 = 0; j2 < 8; ++j2)
          acc += hf[j2] * (float)w0[j2] + hf[8 + j2] * (float)w1[j2];
#pragma unroll
        for (int off = 32; off > 0; off >>= 1) acc += __shfl_xor(acc, off);
        if (lane == 0) ak[n] = tanf_(acc + a.baF[n]);
      }
      __syncthreads();
      float e = -3.0e38f;
      if (tid < S_ && tid < alen) {
        float acc = 0.f;
#pragma unroll 4
        for (int k = 0; k < 100; ++k)
          acc += a.qkT[((size_t)b * 112 + k) * 128 + tid] * ak[k];
        e = acc;
      }
      float r = e;
#pragma unroll
      for (int off = 32; off > 0; off >>= 1) r = fmaxf(r, __shfl_xor(r, off));
      if (tid == 0) red[0] = r;
      if (tid == 64) red[1] = r;
      __syncthreads();
      float mx = fmaxf(red[0], red[1]);
      float ex = (tid < S_ && tid < alen) ? __expf(e - mx) : 0.f;
      if (tid < S_) wts[tid] = ex;
      float sm = ex;
#pragma unroll
      for (int off = 32; off > 0; off >>= 1) sm += __shfl_xor(sm, off);
      if (tid == 0) red[2] = sm;
      if (tid == 64) red[3] = sm;
      __syncthreads();
      float inv = 1.f / (red[2] + red[3]);
      for (int d = tid; d < 320; d += 256) {
        float v = 0.f;
        if (d < 300) {
          const float* qp = a.qvT + ((size_t)b * 304 + d) * 128;
#pragma unroll 8
          for (int s2 = 0; s2 < S_; ++s2) v += wts[s2] * qp[s2];
          v *= inv;
        }
        ctxb[d] = v;
      }
      __syncthreads();
      if (tid < 80) {
        Pack4 pk;
#pragma unroll
        for (int i2 = 0; i2 < 4; ++i2) pk.h[i2] = (__bf16)ctxb[tid * 4 + i2];
        as8((ull*)a.ctx + (size_t)b * 80 + tid, pk.q);
      }
      __syncthreads();   // drain ctx stores before flag
      if (tid == 0) asu(&a.ctxFlag[b], (unsigned)(t + 1));
    }
    // ---- h part (bypass loads) ----
    const ull* hRow8 = (const ull*)(hR + (size_t)am * H_) + quad * 2;
#pragma unroll
    for (int kc = 28; kc < KCD; ++kc) {
      Pack8 u2;
      u2.q[0] = al8(hRow8 + (kc * 8 - 224));
      u2.q[1] = al8(hRow8 + (kc * 8 - 224) + 1);
      bf16x8 b0 = *(const bf16x8*)(Wl + ((size_t)(0 * KCD + kc) * 64 + lane) * 8);
      bf16x8 b1 = *(const bf16x8*)(Wl + ((size_t)(1 * KCD + kc) * 64 + lane) * 8);
      acc0 = __builtin_amdgcn_mfma_f32_16x16x32_bf16(u2.v, b0, acc0, 0, 0, 0);
      acc1 = __builtin_amdgcn_mfma_f32_16x16x32_bf16(u2.v, b1, acc1, 0, 0, 0);
    }
    // ---- wait for ctx rows of this wave, then ctx part ----
    if (lane < 16) {
      while (alu(&a.ctxFlag[m0w + lane]) < (unsigned)(t + 1)) __builtin_amdgcn_s_sleep(1);
    }
    const ull* ctxRow8 = (const ull*)a.ctx + (size_t)am * 80 + quad * 2;
#pragma unroll
    for (int kc = 18; kc < 28; ++kc) {
      Pack8 u2;
      u2.q[0] = al8(ctxRow8 + (kc * 8 - 144));
      u2.q[1] = al8(ctxRow8 + (kc * 8 - 144) + 1);
      bf16x8 b0 = *(const bf16x8*)(Wl + ((size_t)(0 * KCD + kc) * 64 + lane) * 8);
      bf16x8 b1 = *(const bf16x8*)(Wl + ((size_t)(1 * KCD + kc) * 64 + lane) * 8);
      acc0 = __builtin_amdgcn_mfma_f32_16x16x32_bf16(u2.v, b0, acc0, 0, 0, 0);
      acc1 = __builtin_amdgcn_mfma_f32_16x16x32_bf16(u2.v, b1, acc1, 0, 0, 0);
    }
    __syncthreads();   // attention overlay done everywhere in block; reuse zb
#pragma unroll
    for (int r = 0; r < 4; ++r) {
      int ml = wave * 16 + quad * 4 + r;
      zb[ml * 33 + col] = acc0[r];
      zb[ml * 33 + 16 + col] = acc1[r];
    }
    __syncthreads();
#pragma unroll
    for (int p = 0; p < 2; ++p) {
      int ml = (tid >> 3) + p * 32;
      int m = mh * 64 + ml;
      float ig = sigf(zb[ml * 33 + e_u] + bi);
      float fg = sigf(zb[ml * 33 + 8 + e_u] + bff);
      float gg = tanf_(zb[ml * 33 + 16 + e_u] + bg);
      float og = sigf(zb[ml * 33 + 24 + e_u] + bo);
      size_t sidx = (size_t)m * H_ + jj;
      float cOld = a.cD[sidx];
      float c2 = fg * cOld + ig * gg;
      float h2 = og * tanf_(c2);
      a.cD[sidx] = c2;
      hbuf[ml * 8 + e_u] = (__bf16)h2;
      if (!obf) ((float*)a.out)[((size_t)m * T_ + t) * H_ + jj] = h2;
    }
    __syncthreads();
    if (tid < 128) {   // publish h(t+1)
      as8((ull*)(hW + (size_t)pm * H_ + ug * 8) + (tid & 1), ((const ull*)hbuf)[tid]);
    }
    __syncthreads();   // drain publish
    garrive(a.bar, bb);
    // deferred: out store (vector)
    if (obf && tid < 64) {
      int m = mh * 64 + tid;
      *(uint4*)((__bf16*)a.out + ((size_t)m * T_ + t) * H_ + ug * 8) =
          *(const uint4*)(hbuf + tid * 8);
    }
    if (t != T_ - 1) {
      // pre-compute ans part for t+1
      acc0 = f32x4{0.f, 0.f, 0.f, 0.f}; acc1 = acc0;
      const __bf16* aRow = a.ansP + ((size_t)(t + 1) * B_ + am) * 576 + koff;
#pragma unroll
      for (int kc = 0; kc < 18; ++kc) {
        bf16x8 af = *(const bf16x8*)(aRow + kc * 32);
        bf16x8 b0 = *(const bf16x8*)(Wl + ((size_t)(0 * KCD + kc) * 64 + lane) * 8);
        bf16x8 b1 = *(const bf16x8*)(Wl + ((size_t)(1 * KCD + kc) * 64 + lane) * 8);
        acc0 = __builtin_amdgcn_mfma_f32_16x16x32_bf16(af, b0, acc0, 0, 0, 0);
        acc1 = __builtin_amdgcn_mfma_f32_16x16x32_bf16(af, b1, acc1, 0, 0, 0);
      }
      gwait(a.bar, 8u * (unsigned)(t + 1));
    }
  }
}

// ---------------------------------------------------------------------------
extern "C" void kernel_launch(void* const* d_in, const int* in_sizes, int n_in,
                              void* d_out, int out_size, void* d_ws, size_t ws_size,
                              hipStream_t stream) {
  const int* src_seqs = (const int*)d_in[0];
  const int* src_len  = (const int*)d_in[1];
  const int* trg_nt   = (const int*)d_in[2];
  const int* par_nt   = (const int*)d_in[3];
  const int* par_lex  = (const int*)d_in[4];
  const void* lex_emb = d_in[5];
  const void* nt_emb  = d_in[6];
  const void* encWih  = d_in[7];
  const void* encWhh  = d_in[8];
  const void* encB    = d_in[9];
  const void* decWih  = d_in[10];
  const void* decWhh  = d_in[11];
  const void* decB    = d_in[12];
  const void* Wh1 = d_in[13]; const void* bh1 = d_in[14];
  const void* Wh2 = d_in[15]; const void* bh2 = d_in[16];
  const void* Wc1 = d_in[17]; const void* bc1 = d_in[18];
  const void* Wc2 = d_in[19]; const void* bc2 = d_in[20];
  const void* Wa  = d_in[21]; const void* ba  = d_in[22];
  const void* Wqk = d_in[23]; const void* bqk = d_in[24];
  const void* Wqv = d_in[25]; const void* bqv = d_in[26];

  char* base = (char*)d_ws;
  size_t off = 0;
  auto alloc = [&](size_t bytes) -> char* {
    char* p = base + off;
    off += (bytes + 255) & ~(size_t)255;
    return p;
  };
  __bf16* wEnc = (__bf16*)alloc((size_t)4096 * KE_ * 2);
  float*  bEncF = (float*)alloc(4096 * 4);
  __bf16* wDec = (__bf16*)alloc((size_t)4096 * KD_ * 2);
  float*  bDecF = (float*)alloc(4096 * 4);
  __bf16* embE = (__bf16*)alloc((size_t)S_ * B_ * 320 * 2);
  __bf16* ansP = (__bf16*)alloc((size_t)T_ * B_ * 576 * 2);
  __bf16* SH   = (__bf16*)alloc((size_t)B_ * S_ * H_ * 2);   // [s][b][h]
  __bf16* wh1p = (__bf16*)alloc((size_t)2048 * 1024 * 2);
  __bf16* wh2p = (__bf16*)alloc((size_t)1024 * 2048 * 2);
  __bf16* wc1p = (__bf16*)alloc((size_t)2048 * 1024 * 2);
  __bf16* wc2p = (__bf16*)alloc((size_t)1024 * 2048 * 2);
  __bf16* wqkp = (__bf16*)alloc((size_t)112 * 1024 * 2);
  __bf16* wqvp = (__bf16*)alloc((size_t)304 * 1024 * 2);
  __bf16* waB  = (__bf16*)alloc((size_t)112 * 1024 * 2);
  float*  qkT  = (float*)alloc((size_t)B_ * 112 * 128 * 4);  // [b][k][s]
  float*  qvT  = (float*)alloc((size_t)B_ * 304 * 128 * 4);  // [b][d][s]
  __bf16* hE0 = (__bf16*)alloc((size_t)B_ * H_ * 2);
  __bf16* hE1 = (__bf16*)alloc((size_t)B_ * H_ * 2);
  float*  cE  = (float*)alloc((size_t)B_ * H_ * 4);
  __bf16* cEb = (__bf16*)alloc((size_t)B_ * H_ * 2);
  __bf16* t1b = (__bf16*)alloc((size_t)B_ * 2048 * 2);
  __bf16* t2b = (__bf16*)alloc((size_t)B_ * 2048 * 2);
  __bf16* hD0 = (__bf16*)alloc((size_t)B_ * H_ * 2);
  __bf16* hD1 = (__bf16*)alloc((size_t)B_ * H_ * 2);
  float*  cD  = (float*)alloc((size_t)B_ * H_ * 4);
  __bf16* ctx = (__bf16*)alloc((size_t)B_ * 320 * 2);
  float*  bh1F = (float*)alloc(2048 * 4);
  float*  bh2F = (float*)alloc(1024 * 4);
  float*  bc1F = (float*)alloc(2048 * 4);
  float*  bc2F = (float*)alloc(1024 * 4);
  float*  baF  = (float*)alloc(112 * 4);
  float*  bqkF = (float*)alloc(112 * 4);
  float*  bqvF = (float*)alloc(304 * 4);
  unsigned* bar = (unsigned*)alloc(2304 * 4);  // enc[0..1023], dec[1024..2047], ctxFlag[2048..2175]
  int*    flag = (int*)alloc(256);
  if (off > ws_size) return;

  // ---- prep ----
  sniff<<<1, 64, 0, stream>>>(lex_emb, flag);
  zero_bar<<<3, 1024, 0, stream>>>(bar);
  cvt_to_f32<<<16, 256, 0, stream>>>(encB, bEncF, 4096, flag);
  cvt_to_f32<<<16, 256, 0, stream>>>(decB, bDecF, 4096, flag);
  cvt_to_f32<<<8, 256, 0, stream>>>(bh1, bh1F, 2048, flag);
  cvt_to_f32<<<4, 256, 0, stream>>>(bh2, bh2F, 1024, flag);
  cvt_to_f32<<<8, 256, 0, stream>>>(bc1, bc1F, 2048, flag);
  cvt_to_f32<<<4, 256, 0, stream>>>(bc2, bc2F, 1024, flag);
  cvt_to_f32<<<1, 256, 0, stream>>>(ba, baF, 100, flag);
  cvt_to_f32<<<1, 256, 0, stream>>>(bqk, bqkF, 100, flag);
  cvt_to_f32<<<2, 256, 0, stream>>>(bqv, bqvF, 300, flag);
  build_w_enc_sw<<<256, 512, 0, stream>>>(encWih, encWhh, wEnc, flag);
  build_w_dec_sw<<<256, 512, 0, stream>>>(decWih, decWhh, wDec, flag);
  pad_cvt<<<2048, 256, 0, stream>>>(Wh1, wh1p, 2048, 1024, 1024, flag);
  pad_cvt<<<1024, 256, 0, stream>>>(Wh2, wh2p, 1024, 2048, 2048, flag);
  pad_cvt<<<2048, 256, 0, stream>>>(Wc1, wc1p, 2048, 1024, 1024, flag);
  pad_cvt<<<1024, 256, 0, stream>>>(Wc2, wc2p, 1024, 2048, 2048, flag);
  pad_cvt<<<112, 256, 0, stream>>>(Wqk, wqkp, 100, 1024, 1024, flag);
  pad_cvt<<<304, 256, 0, stream>>>(Wqv, wqvp, 300, 1024, 1024, flag);
  pad_cvt<<<100, 256, 0, stream>>>(Wa, waB, 100, 1024, 1024, flag);
  gather_emb<<<S_ * B_, 256, 0, stream>>>(lex_emb, src_seqs, embE, flag);
  gather_ans<<<T_ * B_, 256, 0, stream>>>(nt_emb, lex_emb, trg_nt, par_nt, par_lex, ansP, flag);
  zero_state<<<512, 256, 0, stream>>>(hE0, cE);

  const unsigned encLds = 2 * KCE * 512 * 2 + 64 * 33 * 4 + 1024;   // 95488 B
  const unsigned decLds = 2 * KCD * 512 * 2 + 64 * 33 * 4 + 1024;   // 132352 B
  hipFuncSetAttribute((const void*)enc_coop, hipFuncAttributeMaxDynamicSharedMemorySize, encLds);
  hipFuncSetAttribute((const void*)dec_coop, hipFuncAttributeMaxDynamicSharedMemorySize, decLds);

  // ---- encoder: one launch, 128 steps ----
  EncArgs ea = {wEnc, bEncF, embE, hE0, hE1, cE, src_len, SH, bar};
  void* eargs[] = {&ea};
  hipLaunchCooperativeKernel((const void*)enc_coop, dim3(256), dim3(256), eargs, encLds, stream);

  // ---- decoder init MLPs (final enc state in hE0 / cE) ----
  f2b<<<512, 256, 0, stream>>>(cE, cEb, B_ * H_);
  gemm16<1, true, false, 0><<<dim3(128, 2), 256, 0, stream>>>(hE0, 1024, wh1p, 1024, bh1F, 2048, t1b, nullptr, 2048);
  gemm16<0, true, false, 0><<<dim3(64, 2), 256, 0, stream>>>(t1b, 2048, wh2p, 2048, bh2F, 1024, hD0, nullptr, 1024);
  gemm16<1, true, false, 0><<<dim3(128, 2), 256, 0, stream>>>(cEb, 1024, wc1p, 1024, bc1F, 2048, t2b, nullptr, 2048);
  gemm16<0, false, true, 0><<<dim3(64, 2), 256, 0, stream>>>(t2b, 2048, wc2p, 2048, bc2F, 1024, nullptr, cD, 1024);

  // ---- attention keys/values, written transposed: qkT[b][k][s], qvT[b][d][s] ----
  gemm16<2, false, true, 1><<<dim3(7, 256), 256, 0, stream>>>(SH, 1024, wqkp, 1024, bqkF, 100, nullptr, qkT, 112);
  gemm16<0, false, true, 1><<<dim3(19, 256), 256, 0, stream>>>(SH, 1024, wqvp, 1024, bqvF, 300, nullptr, qvT, 304);

  // ---- decoder: one launch, 64 steps, in-kernel attention, 1 barrier/step ----
  DecArgs da = {wDec, bDecF, ansP, hD0, hD1, cD, src_len,
                waB, baF, qkT, qvT, ctx, d_out, flag, bar + 1024, bar + 2048};
  void* dargs[] = {&da};
  hipLaunchCooperativeKernel((const void*)dec_coop, dim3(256), dim3(256), dargs, decLds, stream);
}